// Round 1
// baseline (6786.671 us; speedup 1.0000x reference)
//
#include <hip/hip_runtime.h>
#include <math.h>

#define NB 64
#define NV 128
#define NEDGE_PER 8128
#define N_EDGE (NB * NEDGE_PER)   // 520192
#define N_EX (NB * NV)            // 8192

// workspace layout (doubles):
// ws[0..63]    per-sample SmoothL1 sums
// ws[64]       existence BCE sum
// ws[128..383] edge BCE partials (256 blocks)

__device__ __forceinline__ float sl1f(float d) {
    d = fabsf(d);
    return d < 1.0f ? 0.5f * d * d : d - 0.5f;
}

// One wave (64 lanes) per batch sample. Exact JV Hungarian in f64,
// mirroring the reference _lap() including argmin lowest-index tie-break.
__global__ __launch_bounds__(64) void hungarian_kernel(
    const float* __restrict__ pv,   // [B,V,3]
    const float* __restrict__ pe,   // [B,V]
    const float* __restrict__ tv,   // [B,V,3]
    const int*   __restrict__ counts, // [B]
    double* __restrict__ ws_sl1)    // [B]
{
    const int b = blockIdx.x;
    const int lane = threadIdx.x;
    const int c = counts[b];

    __shared__ float4 s_row[NV];    // pred row: x,y,z,|pe-1|
    __shared__ float  s_pedum[NV];  // pe (dummy-column cost)
    __shared__ int    s_p[NV + 1];
    __shared__ int    s_way[NV + 1];
    __shared__ double s_u[NV + 1];

    const float* pvb = pv + (size_t)b * NV * 3;
    const float* peb = pe + (size_t)b * NV;
    const float* tvb = tv + (size_t)b * NV * 3;

    // stage per-row data (single wave: program order => no barrier needed)
    for (int r = lane; r < NV; r += 64) {
        float x = pvb[r * 3 + 0], y = pvb[r * 3 + 1], z = pvb[r * 3 + 2];
        float e = peb[r];
        s_row[r] = make_float4(x, y, z, fabsf(e - 1.0f));
        s_pedum[r] = e;
    }
    for (int j = lane; j <= NV; j += 64) { s_p[j] = 0; s_u[j] = 0.0; }

    // per-lane columns: jA = lane+1, jB = lane+65 (1-indexed cols 1..128)
    const int jA = lane + 1, jB = lane + 65;
    const float tAx = tvb[(jA - 1) * 3 + 0], tAy = tvb[(jA - 1) * 3 + 1], tAz = tvb[(jA - 1) * 3 + 2];
    const float tBx = tvb[(jB - 1) * 3 + 0], tBy = tvb[(jB - 1) * 3 + 1], tBz = tvb[(jB - 1) * 3 + 2];
    const bool dumA = (jA > c), dumB = (jB > c);
    const int rA = lane + 1, rB = lane + 65;   // rows this lane owns for u-updates

    const double INF = 1e18;
    double vA = 0.0, vB = 0.0;

    for (int i = 1; i <= NV; ++i) {
        if (lane == 0) s_p[0] = i;
        double minvA = INF, minvB = INF;
        bool usedA = false, usedB = false;
        bool rowUsedA = false, rowUsedB = false;
        int j0 = 0;

        for (;;) {
            // used[j0] = true (register flags; col 0 needs no flag)
            usedA = usedA || (j0 == jA);
            usedB = usedB || (j0 == jB);
            const int i0 = s_p[j0];
            rowUsedA = rowUsedA || (i0 == rA);
            rowUsedB = rowUsedB || (i0 == rB);
            const double u0 = s_u[i0];
            const float4 row = s_row[i0 - 1];
            const float pdum = s_pedum[i0 - 1];

            double candA = INF, candB = INF;
            if (!usedA) {
                float cf = dumA ? pdum
                                : (fabsf(row.x - tAx) + fabsf(row.y - tAy) + fabsf(row.z - tAz) + row.w);
                double cur = (double)cf - u0 - vA;
                if (cur < minvA) { minvA = cur; s_way[jA] = j0; }
                candA = minvA;
            }
            if (!usedB) {
                float cf = dumB ? pdum
                                : (fabsf(row.x - tBx) + fabsf(row.y - tBy) + fabsf(row.z - tBz) + row.w);
                double cur = (double)cf - u0 - vB;
                if (cur < minvB) { minvB = cur; s_way[jB] = j0; }
                candB = minvB;
            }

            // lexicographic (value, index) min; jA < jB so tie keeps jA
            double val; int idx;
            if (candB < candA) { val = candB; idx = jB; } else { val = candA; idx = jA; }
            for (int off = 1; off < 64; off <<= 1) {
                double oval = __shfl_xor(val, off);
                int    oidx = __shfl_xor(idx, off);
                if (oval < val || (oval == val && oidx < idx)) { val = oval; idx = oidx; }
            }
            const double delta = val;

            // u[p[used]] += delta  (rows visited so far, all distinct)
            if (rowUsedA) s_u[rA] += delta;
            if (rowUsedB) s_u[rB] += delta;
            // v[used] -= delta ; minv[~used] -= delta
            if (usedA) vA -= delta; else minvA -= delta;
            if (usedB) vB -= delta; else minvB -= delta;

            j0 = idx;
            if (s_p[j0] == 0) break;
        }

        // augment along way[] chain (lane 0; same-wave LDS order is safe)
        if (lane == 0) {
            int j = j0;
            while (j != 0) {
                int j1 = s_way[j];
                s_p[j] = s_p[j1];
                j = j1;
            }
        }
    }

    // SmoothL1 over matched pairs: target col t (0-based) matched to pred s_p[t+1]-1
    double acc = 0.0;
    if (lane < c) {
        int pr = s_p[lane + 1] - 1;
        float4 prow = s_row[pr];
        acc += (double)(sl1f(prow.x - tAx) + sl1f(prow.y - tAy) + sl1f(prow.z - tAz));
    }
    if (lane + 64 < c) {
        int pr = s_p[lane + 65] - 1;
        float4 prow = s_row[pr];
        acc += (double)(sl1f(prow.x - tBx) + sl1f(prow.y - tBy) + sl1f(prow.z - tBz));
    }
    for (int off = 1; off < 64; off <<= 1) acc += __shfl_xor(acc, off);
    if (lane == 0) ws_sl1[b] = acc;
}

__device__ __forceinline__ double bce_term(float p, float t) {
    float logp = fmaxf(logf(p), -100.0f);
    float logq = fmaxf(logf(1.0f - p), -100.0f);
    return (double)(-(t * logp + (1.0f - t) * logq));
}

__global__ __launch_bounds__(256) void bce_exist_kernel(
    const float* __restrict__ pe, const int* __restrict__ te, double* __restrict__ out)
{
    const int tid = threadIdx.x;
    double acc = 0.0;
    for (int i = tid; i < N_EX; i += 256)
        acc += bce_term(pe[i], (float)te[i]);
    for (int off = 1; off < 64; off <<= 1) acc += __shfl_xor(acc, off);
    __shared__ double s[4];
    if ((tid & 63) == 0) s[tid >> 6] = acc;
    __syncthreads();
    if (tid == 0) out[0] = s[0] + s[1] + s[2] + s[3];
}

__global__ __launch_bounds__(256) void bce_edge_kernel(
    const float* __restrict__ p, const float* __restrict__ t, double* __restrict__ out)
{
    const int tid = threadIdx.x;
    double acc = 0.0;
    for (int i = blockIdx.x * 256 + tid; i < N_EDGE; i += 256 * 256)
        acc += bce_term(p[i], t[i]);
    for (int off = 1; off < 64; off <<= 1) acc += __shfl_xor(acc, off);
    __shared__ double s[4];
    if ((tid & 63) == 0) s[tid >> 6] = acc;
    __syncthreads();
    if (tid == 0) out[blockIdx.x] = s[0] + s[1] + s[2] + s[3];
}

__global__ __launch_bounds__(64) void finalize_kernel(
    const double* __restrict__ ws, const int* __restrict__ counts, float* __restrict__ out)
{
    const int lane = threadIdx.x;
    double vsum = ws[lane];
    double csum = (double)counts[lane];
    double edsum = 0.0;
    for (int k = lane; k < 256; k += 64) edsum += ws[128 + k];
    for (int off = 1; off < 64; off <<= 1) {
        vsum  += __shfl_xor(vsum, off);
        csum  += __shfl_xor(csum, off);
        edsum += __shfl_xor(edsum, off);
    }
    if (lane == 0) {
        double vloss  = vsum / (3.0 * csum);
        double eloss  = ws[64] / (double)N_EX;
        double edloss = edsum / (double)N_EDGE;
        double total  = vloss + eloss + edloss;
        out[0] = (float)total;
        out[1] = (float)vloss;
        out[2] = (float)eloss;
        out[3] = (float)edloss;
    }
}

extern "C" void kernel_launch(void* const* d_in, const int* in_sizes, int n_in,
                              void* d_out, int out_size, void* d_ws, size_t ws_size,
                              hipStream_t stream) {
    const float* pv     = (const float*)d_in[0]; // pred_vertices  [B,V,3]
    const float* pe     = (const float*)d_in[1]; // pred_existence [B,V]
    const float* pedge  = (const float*)d_in[2]; // pred_edge_probs [B,E]
    const float* tv     = (const float*)d_in[3]; // target_vertices [B,V,3]
    const int*   te     = (const int*)d_in[4];   // target_existence [B,V]
    const float* elab   = (const float*)d_in[5]; // edge_labels [B,E]
    const int*   counts = (const int*)d_in[6];   // vertex_counts [B]
    double* ws = (double*)d_ws;
    float* out = (float*)d_out;

    hipLaunchKernelGGL(hungarian_kernel, dim3(NB), dim3(64), 0, stream, pv, pe, tv, counts, ws);
    hipLaunchKernelGGL(bce_exist_kernel, dim3(1), dim3(256), 0, stream, pe, te, ws + 64);
    hipLaunchKernelGGL(bce_edge_kernel, dim3(256), dim3(256), 0, stream, pedge, elab, ws + 128);
    hipLaunchKernelGGL(finalize_kernel, dim3(1), dim3(64), 0, stream, ws, counts, out);
}

// Round 2
// 5799.014 us; speedup vs baseline: 1.1703x; 1.1703x over previous
//
#include <hip/hip_runtime.h>
#include <math.h>

#define NB 64
#define NV 128
#define NEDGE_PER 8128
#define N_EDGE (NB * NEDGE_PER)   // 520192
#define N_EX (NB * NV)            // 8192

// workspace layout (doubles):
// ws[0..63]    per-sample SmoothL1 sums
// ws[64]       existence BCE sum
// ws[128..383] edge BCE partials (256 blocks)

typedef unsigned int uint2v __attribute__((ext_vector_type(2)));

__device__ __forceinline__ float sl1f(float d) {
    d = fabsf(d);
    return d < 1.0f ? 0.5f * d * d : d - 0.5f;
}

// ---- VALU-only cross-lane helpers ----------------------------------------

template <int CTRL>
__device__ __forceinline__ int dpp_i(int x) {
    return __builtin_amdgcn_update_dpp(0, x, CTRL, 0xF, 0xF, true);
}
template <int CTRL>
__device__ __forceinline__ double dpp_d(double x) {
    int lo = dpp_i<CTRL>(__double2loint(x));
    int hi = dpp_i<CTRL>(__double2hiint(x));
    return __hiloint2double(hi, lo);
}

__device__ __forceinline__ void lexmin(double& val, int& idx, double ov, int oi) {
    if (ov < val || (ov == val && oi < idx)) { val = ov; idx = oi; }
}

// 64-lane lexicographic (val,idx) argmin, result broadcast to all lanes.
// Steps 1,2: quad_perm xor1/xor2. Steps 3,4: row mirrors (valid because groups
// are uniform after earlier steps). Steps 5,6: permlane swaps — we lexmin
// against BOTH outputs so either swap orientation is correct.
__device__ __forceinline__ void wave_argmin(double& val, int& idx) {
    { double ov = dpp_d<0xB1>(val);  int oi = dpp_i<0xB1>(idx);  lexmin(val, idx, ov, oi); }  // xor1
    { double ov = dpp_d<0x4E>(val);  int oi = dpp_i<0x4E>(idx);  lexmin(val, idx, ov, oi); }  // xor2
    { double ov = dpp_d<0x141>(val); int oi = dpp_i<0x141>(idx); lexmin(val, idx, ov, oi); }  // row_half_mirror (^4 eff.)
    { double ov = dpp_d<0x140>(val); int oi = dpp_i<0x140>(idx); lexmin(val, idx, ov, oi); }  // row_mirror (^8 eff.)
#if __has_builtin(__builtin_amdgcn_permlane16_swap)
    {
        uint2v lo = __builtin_amdgcn_permlane16_swap((unsigned)__double2loint(val), (unsigned)__double2loint(val), false, false);
        uint2v hi = __builtin_amdgcn_permlane16_swap((unsigned)__double2hiint(val), (unsigned)__double2hiint(val), false, false);
        uint2v ii = __builtin_amdgcn_permlane16_swap((unsigned)idx, (unsigned)idx, false, false);
        lexmin(val, idx, __hiloint2double((int)hi.x, (int)lo.x), (int)ii.x);
        lexmin(val, idx, __hiloint2double((int)hi.y, (int)lo.y), (int)ii.y);
    }
#else
    { double ov = __shfl_xor(val, 16); int oi = __shfl_xor(idx, 16); lexmin(val, idx, ov, oi); }
#endif
#if __has_builtin(__builtin_amdgcn_permlane32_swap)
    {
        uint2v lo = __builtin_amdgcn_permlane32_swap((unsigned)__double2loint(val), (unsigned)__double2loint(val), false, false);
        uint2v hi = __builtin_amdgcn_permlane32_swap((unsigned)__double2hiint(val), (unsigned)__double2hiint(val), false, false);
        uint2v ii = __builtin_amdgcn_permlane32_swap((unsigned)idx, (unsigned)idx, false, false);
        lexmin(val, idx, __hiloint2double((int)hi.x, (int)lo.x), (int)ii.x);
        lexmin(val, idx, __hiloint2double((int)hi.y, (int)lo.y), (int)ii.y);
    }
#else
    { double ov = __shfl_xor(val, 32); int oi = __shfl_xor(idx, 32); lexmin(val, idx, ov, oi); }
#endif
}

__device__ __forceinline__ int rl_i(int v, int sl) {
    return __builtin_amdgcn_readlane(v, sl);
}
__device__ __forceinline__ float rl_f(float v, int sl) {
    return __int_as_float(__builtin_amdgcn_readlane(__float_as_int(v), sl));
}
__device__ __forceinline__ double rl_d(double v, int sl) {
    return __hiloint2double(__builtin_amdgcn_readlane(__double2hiint(v), sl),
                            __builtin_amdgcn_readlane(__double2loint(v), sl));
}

// ---- Hungarian (JV) — one wave per sample, everything in registers --------

__global__ __launch_bounds__(64) void hungarian_kernel(
    const float* __restrict__ pv,     // [B,V,3]
    const float* __restrict__ pe,     // [B,V]
    const float* __restrict__ tv,     // [B,V,3]
    const int*   __restrict__ counts, // [B]
    double* __restrict__ ws_sl1)      // [B]
{
    const int b = blockIdx.x;
    const int lane = threadIdx.x;
    const int c = counts[b];

    __shared__ float4 s_row[NV];   // only for the final SmoothL1 gather

    const float* pvb = pv + (size_t)b * NV * 3;
    const float* peb = pe + (size_t)b * NV;
    const float* tvb = tv + (size_t)b * NV * 3;

    // lane owns rows/cols (1-based) rA=jA=lane+1 and rB=jB=lane+65
    float rAx = pvb[lane * 3 + 0], rAy = pvb[lane * 3 + 1], rAz = pvb[lane * 3 + 2];
    float rBx = pvb[(lane + 64) * 3 + 0], rBy = pvb[(lane + 64) * 3 + 1], rBz = pvb[(lane + 64) * 3 + 2];
    float peA = peb[lane], peB = peb[lane + 64];
    float rAw = fabsf(peA - 1.0f), rBw = fabsf(peB - 1.0f);
    s_row[lane]      = make_float4(rAx, rAy, rAz, rAw);
    s_row[lane + 64] = make_float4(rBx, rBy, rBz, rBw);

    const float tAx = tvb[lane * 3 + 0], tAy = tvb[lane * 3 + 1], tAz = tvb[lane * 3 + 2];
    const float tBx = tvb[(lane + 64) * 3 + 0], tBy = tvb[(lane + 64) * 3 + 1], tBz = tvb[(lane + 64) * 3 + 2];

    const int jA = lane + 1, jB = lane + 65;
    const int rA = lane + 1, rB = lane + 65;
    const bool dumA = (jA > c), dumB = (jB > c);

    const double INF = 1e18;
    double vA = 0.0, vB = 0.0;   // column potentials v[jA], v[jB]
    double uA = 0.0, uB = 0.0;   // row potentials u[rA], u[rB]
    int pA = 0, pB = 0;          // p[jA], p[jB] (row matched to column, 1-based, 0 = none)
    int wayA = 0, wayB = 0;      // way[jA], way[jB]

    for (int i = 1; i <= NV; ++i) {
        double minvA = INF, minvB = INF;
        bool usedA = false, usedB = false;
        bool rowUsedA = false, rowUsedB = false;

        int j0 = 0;
        int i0 = i;                 // p[0] = i
        rowUsedA = (rA == i0);
        rowUsedB = (rB == i0);

        // fetch row i0's data + u[i0] from the owning lane (uniform index)
        float rx, ry, rz, rw, rp; double u0;
        {
            const bool hi = (i0 > 64);
            const int sl = (i0 - 1) & 63;
            rx = rl_f(hi ? rBx : rAx, sl);
            ry = rl_f(hi ? rBy : rAy, sl);
            rz = rl_f(hi ? rBz : rAz, sl);
            rw = rl_f(hi ? rBw : rAw, sl);
            rp = rl_f(hi ? peB : peA, sl);
            u0 = rl_d(hi ? uB : uA, sl);
        }

        for (;;) {
            // candidate reduced costs for this lane's two columns vs row i0.
            // exact op order matches the reference: ((|dx|+|dy|)+|dz|)+w in f32,
            // then f64 ((cf - u0) - v).
            double candA = INF, candB = INF;
            if (!usedA) {
                float cf = dumA ? rp : (((fabsf(rx - tAx) + fabsf(ry - tAy)) + fabsf(rz - tAz)) + rw);
                double cur = ((double)cf - u0) - vA;
                if (cur < minvA) { minvA = cur; wayA = j0; }
                candA = minvA;
            }
            if (!usedB) {
                float cf = dumB ? rp : (((fabsf(rx - tBx) + fabsf(ry - tBy)) + fabsf(rz - tBz)) + rw);
                double cur = ((double)cf - u0) - vB;
                if (cur < minvB) { minvB = cur; wayB = j0; }
                candB = minvB;
            }

            // lane-local pick (jA < jB: tie keeps A), then wave argmin
            double val; int idx;
            if (candB < candA) { val = candB; idx = jB; }
            else               { val = candA; idx = jA; }
            wave_argmin(val, idx);
            const double delta = val;

            // u[p[used]] += delta ; v[used] -= delta ; minv[free] -= delta
            if (rowUsedA) uA += delta;
            if (rowUsedB) uB += delta;
            if (usedA) vA -= delta; else minvA -= delta;
            if (usedB) vB -= delta; else minvB -= delta;

            j0 = idx;
            {
                const bool hij = (j0 > 64);
                const int slj = (j0 - 1) & 63;
                i0 = rl_i(hij ? pB : pA, slj);
            }
            if (i0 == 0) break;

            usedA |= (j0 == jA);
            usedB |= (j0 == jB);
            rowUsedA |= (i0 == rA);
            rowUsedB |= (i0 == rB);
            {
                const bool hi = (i0 > 64);
                const int sl = (i0 - 1) & 63;
                rx = rl_f(hi ? rBx : rAx, sl);
                ry = rl_f(hi ? rBy : rAy, sl);
                rz = rl_f(hi ? rBz : rAz, sl);
                rw = rl_f(hi ? rBw : rAw, sl);
                rp = rl_f(hi ? peB : peA, sl);
                u0 = rl_d(hi ? uB : uA, sl);
            }
        }

        // augment along way[] chain — wave-uniform register walk
        int j = j0;
        while (j != 0) {
            int j1 = rl_i((j <= 64) ? wayA : wayB, (j - 1) & 63);
            int pnew;
            if (j1 == 0) pnew = i;  // p[0] = i
            else pnew = rl_i((j1 <= 64) ? pA : pB, (j1 - 1) & 63);
            if (jA == j) pA = pnew;
            if (jB == j) pB = pnew;
            j = j1;
        }
    }

    // SmoothL1 over matched pairs: target col t (0-based) matched to pred p[t+1]-1
    double acc = 0.0;
    if (lane < c) {
        float4 prow = s_row[pA - 1];
        acc += (double)(sl1f(prow.x - tAx) + sl1f(prow.y - tAy) + sl1f(prow.z - tAz));
    }
    if (lane + 64 < c) {
        float4 prow = s_row[pB - 1];
        acc += (double)(sl1f(prow.x - tBx) + sl1f(prow.y - tBy) + sl1f(prow.z - tBz));
    }
    for (int off = 1; off < 64; off <<= 1) acc += __shfl_xor(acc, off);
    if (lane == 0) ws_sl1[b] = acc;
}

// ---- BCE / finalize -------------------------------------------------------

__device__ __forceinline__ double bce_term(float p, float t) {
    float logp = fmaxf(logf(p), -100.0f);
    float logq = fmaxf(logf(1.0f - p), -100.0f);
    return (double)(-(t * logp + (1.0f - t) * logq));
}

__global__ __launch_bounds__(256) void bce_exist_kernel(
    const float* __restrict__ pe, const int* __restrict__ te, double* __restrict__ out)
{
    const int tid = threadIdx.x;
    double acc = 0.0;
    for (int i = tid; i < N_EX; i += 256)
        acc += bce_term(pe[i], (float)te[i]);
    for (int off = 1; off < 64; off <<= 1) acc += __shfl_xor(acc, off);
    __shared__ double s[4];
    if ((tid & 63) == 0) s[tid >> 6] = acc;
    __syncthreads();
    if (tid == 0) out[0] = s[0] + s[1] + s[2] + s[3];
}

__global__ __launch_bounds__(256) void bce_edge_kernel(
    const float* __restrict__ p, const float* __restrict__ t, double* __restrict__ out)
{
    const int tid = threadIdx.x;
    double acc = 0.0;
    for (int i = blockIdx.x * 256 + tid; i < N_EDGE; i += 256 * 256)
        acc += bce_term(p[i], t[i]);
    for (int off = 1; off < 64; off <<= 1) acc += __shfl_xor(acc, off);
    __shared__ double s[4];
    if ((tid & 63) == 0) s[tid >> 6] = acc;
    __syncthreads();
    if (tid == 0) out[blockIdx.x] = s[0] + s[1] + s[2] + s[3];
}

__global__ __launch_bounds__(64) void finalize_kernel(
    const double* __restrict__ ws, const int* __restrict__ counts, float* __restrict__ out)
{
    const int lane = threadIdx.x;
    double vsum = ws[lane];
    double csum = (double)counts[lane];
    double edsum = 0.0;
    for (int k = lane; k < 256; k += 64) edsum += ws[128 + k];
    for (int off = 1; off < 64; off <<= 1) {
        vsum  += __shfl_xor(vsum, off);
        csum  += __shfl_xor(csum, off);
        edsum += __shfl_xor(edsum, off);
    }
    if (lane == 0) {
        double vloss  = vsum / (3.0 * csum);
        double eloss  = ws[64] / (double)N_EX;
        double edloss = edsum / (double)N_EDGE;
        double total  = vloss + eloss + edloss;
        out[0] = (float)total;
        out[1] = (float)vloss;
        out[2] = (float)eloss;
        out[3] = (float)edloss;
    }
}

extern "C" void kernel_launch(void* const* d_in, const int* in_sizes, int n_in,
                              void* d_out, int out_size, void* d_ws, size_t ws_size,
                              hipStream_t stream) {
    const float* pv     = (const float*)d_in[0];
    const float* pe     = (const float*)d_in[1];
    const float* pedge  = (const float*)d_in[2];
    const float* tv     = (const float*)d_in[3];
    const int*   te     = (const int*)d_in[4];
    const float* elab   = (const float*)d_in[5];
    const int*   counts = (const int*)d_in[6];
    double* ws = (double*)d_ws;
    float* out = (float*)d_out;

    hipLaunchKernelGGL(hungarian_kernel, dim3(NB), dim3(64), 0, stream, pv, pe, tv, counts, ws);
    hipLaunchKernelGGL(bce_exist_kernel, dim3(1), dim3(256), 0, stream, pe, te, ws + 64);
    hipLaunchKernelGGL(bce_edge_kernel, dim3(256), dim3(256), 0, stream, pedge, elab, ws + 128);
    hipLaunchKernelGGL(finalize_kernel, dim3(1), dim3(64), 0, stream, ws, counts, out);
}

// Round 3
// 3950.146 us; speedup vs baseline: 1.7181x; 1.4681x over previous
//
#include <hip/hip_runtime.h>
#include <math.h>

#define NB 64
#define NV 128
#define NEDGE_PER 8128
#define N_EDGE (NB * NEDGE_PER)   // 520192
#define N_EX (NB * NV)            // 8192

// workspace layout (doubles):
// ws[0..63]    per-sample SmoothL1 sums
// ws[64]       existence BCE sum
// ws[128..383] edge BCE partials (256 blocks)

typedef unsigned int uint2v __attribute__((ext_vector_type(2)));

__device__ __forceinline__ float sl1f(float d) {
    d = fabsf(d);
    return d < 1.0f ? 0.5f * d * d : d - 0.5f;
}

// ---- VALU-only cross-lane helpers ----------------------------------------

template <int CTRL>
__device__ __forceinline__ int dpp_i(int x) {
    return __builtin_amdgcn_update_dpp(0, x, CTRL, 0xF, 0xF, true);
}
template <int CTRL>
__device__ __forceinline__ unsigned long long dpp_u64(unsigned long long x) {
    int lo = dpp_i<CTRL>((int)(unsigned)x);
    int hi = dpp_i<CTRL>((int)(unsigned)(x >> 32));
    return ((unsigned long long)(unsigned)hi << 32) | (unsigned)lo;
}

// Sortable key: monotone u64 mapping of f64, low 8 bits replaced by column idx
// (1..128). Orders by (value-with-low-8-mantissa-bits-zeroed, idx) — exact ties
// (identical f64, common for dummy columns) break to lowest idx like np.argmin.
// delta is re-read exactly from the winning lane, so potentials stay bit-exact.
__device__ __forceinline__ unsigned long long d2key(double x, int idx) {
    unsigned long long b = (unsigned long long)__double_as_longlong(x);
    unsigned long long m = (unsigned long long)(((long long)b) >> 63) | 0x8000000000000000ull;
    unsigned long long k = b ^ m;
    return (k & ~0xFFull) | (unsigned long long)idx;
}

// 64-lane min over packed keys, result broadcast to all lanes.
// quad_perm xor1/xor2, row mirrors (valid: groups uniform after prior steps),
// then permlane swaps — min against BOTH outputs so orientation is irrelevant.
__device__ __forceinline__ unsigned long long wave_minkey(unsigned long long k) {
    { unsigned long long o = dpp_u64<0xB1>(k);  if (o < k) k = o; }   // quad_perm xor1
    { unsigned long long o = dpp_u64<0x4E>(k);  if (o < k) k = o; }   // quad_perm xor2
    { unsigned long long o = dpp_u64<0x141>(k); if (o < k) k = o; }   // row_half_mirror (^4)
    { unsigned long long o = dpp_u64<0x140>(k); if (o < k) k = o; }   // row_mirror (^8)
#if __has_builtin(__builtin_amdgcn_permlane16_swap)
    {
        unsigned klo = (unsigned)k, khi = (unsigned)(k >> 32);
        uint2v lo = __builtin_amdgcn_permlane16_swap(klo, klo, false, false);
        uint2v hi = __builtin_amdgcn_permlane16_swap(khi, khi, false, false);
        unsigned long long o1 = ((unsigned long long)hi.x << 32) | lo.x;
        unsigned long long o2 = ((unsigned long long)hi.y << 32) | lo.y;
        if (o1 < k) k = o1;
        if (o2 < k) k = o2;
    }
#else
    { unsigned long long o = (unsigned long long)__shfl_xor((long long)k, 16); if (o < k) k = o; }
#endif
#if __has_builtin(__builtin_amdgcn_permlane32_swap)
    {
        unsigned klo = (unsigned)k, khi = (unsigned)(k >> 32);
        uint2v lo = __builtin_amdgcn_permlane32_swap(klo, klo, false, false);
        uint2v hi = __builtin_amdgcn_permlane32_swap(khi, khi, false, false);
        unsigned long long o1 = ((unsigned long long)hi.x << 32) | lo.x;
        unsigned long long o2 = ((unsigned long long)hi.y << 32) | lo.y;
        if (o1 < k) k = o1;
        if (o2 < k) k = o2;
    }
#else
    { unsigned long long o = (unsigned long long)__shfl_xor((long long)k, 32); if (o < k) k = o; }
#endif
    return k;
}

__device__ __forceinline__ int rl_i(int v, int sl) {
    return __builtin_amdgcn_readlane(v, sl);
}
__device__ __forceinline__ float rl_f(float v, int sl) {
    return __int_as_float(__builtin_amdgcn_readlane(__float_as_int(v), sl));
}
__device__ __forceinline__ double rl_d(double v, int sl) {
    return __hiloint2double(__builtin_amdgcn_readlane(__double2hiint(v), sl),
                            __builtin_amdgcn_readlane(__double2loint(v), sl));
}

// ---- Hungarian (JV) — one wave per sample, all state in registers ---------

__global__ __launch_bounds__(64, 1) void hungarian_kernel(
    const float* __restrict__ pv,     // [B,V,3]
    const float* __restrict__ pe,     // [B,V]
    const float* __restrict__ tv,     // [B,V,3]
    const int*   __restrict__ counts, // [B]
    double* __restrict__ ws_sl1)      // [B]
{
    const int b = blockIdx.x;
    const int lane = threadIdx.x;
    const int c = counts[b];

    __shared__ float4 s_row[NV];   // only for the final SmoothL1 gather

    const float* pvb = pv + (size_t)b * NV * 3;
    const float* peb = pe + (size_t)b * NV;
    const float* tvb = tv + (size_t)b * NV * 3;

    // lane owns rows/cols (1-based) rA=jA=lane+1 and rB=jB=lane+65
    float rAx = pvb[lane * 3 + 0], rAy = pvb[lane * 3 + 1], rAz = pvb[lane * 3 + 2];
    float rBx = pvb[(lane + 64) * 3 + 0], rBy = pvb[(lane + 64) * 3 + 1], rBz = pvb[(lane + 64) * 3 + 2];
    float peA = peb[lane], peB = peb[lane + 64];
    float rAw = fabsf(peA - 1.0f), rBw = fabsf(peB - 1.0f);
    s_row[lane]      = make_float4(rAx, rAy, rAz, rAw);
    s_row[lane + 64] = make_float4(rBx, rBy, rBz, rBw);

    const float tAx = tvb[lane * 3 + 0], tAy = tvb[lane * 3 + 1], tAz = tvb[lane * 3 + 2];
    const float tBx = tvb[(lane + 64) * 3 + 0], tBy = tvb[(lane + 64) * 3 + 1], tBz = tvb[(lane + 64) * 3 + 2];

    const int jA = lane + 1, jB = lane + 65;
    const int rA = lane + 1, rB = lane + 65;
    const bool dumA = (jA > c), dumB = (jB > c);

    const double INF = 1e18;
    double vA = 0.0, vB = 0.0;   // column potentials
    double uA = 0.0, uB = 0.0;   // row potentials
    int pA = 0, pB = 0;          // p[jA], p[jB] (1-based row, 0 = none)
    int wayA = 0, wayB = 0;

    for (int i = 1; i <= NV; ++i) {
        double minvA = INF, minvB = INF;
        bool usedA = false, usedB = false;
        bool rowUsedA, rowUsedB;

        int j0 = 0;
        int i0 = i;                 // p[0] = i
        rowUsedA = (rA == i0);
        rowUsedB = (rB == i0);

        // broadcast row i0's data + u[i0] from the owning lane (uniform index)
        float rx, ry, rz, rw, rp; double u0;
        {
            const bool hi = (i0 > 64);
            const int sl = (i0 - 1) & 63;
            rx = rl_f(hi ? rBx : rAx, sl);
            ry = rl_f(hi ? rBy : rAy, sl);
            rz = rl_f(hi ? rBz : rAz, sl);
            rw = rl_f(hi ? rBw : rAw, sl);
            rp = rl_f(hi ? peB : peA, sl);
            u0 = rl_d(hi ? uB : uA, sl);
        }

        for (;;) {
            // reduced costs, exact reference op order:
            // f32 ((|dx|+|dy|)+|dz|)+w, then f64 ((cf - u0) - v)
            if (!usedA) {
                float cf = dumA ? rp : (((fabsf(rx - tAx) + fabsf(ry - tAy)) + fabsf(rz - tAz)) + rw);
                double cur = ((double)cf - u0) - vA;
                if (cur < minvA) { minvA = cur; wayA = j0; }
            }
            if (!usedB) {
                float cf = dumB ? rp : (((fabsf(rx - tBx) + fabsf(ry - tBy)) + fabsf(rz - tBz)) + rw);
                double cur = ((double)cf - u0) - vB;
                if (cur < minvB) { minvB = cur; wayB = j0; }
            }

            unsigned long long kA = usedA ? ~0ull : d2key(minvA, jA);
            unsigned long long kB = usedB ? ~0ull : d2key(minvB, jB);
            unsigned long long k = (kB < kA) ? kB : kA;
            k = wave_minkey(k);

            const int idx = (int)(__builtin_amdgcn_readfirstlane((unsigned)k) & 0xFFu);
            const bool hij = (idx > 64);
            const int slj = (idx - 1) & 63;
            // exact f64 delta = minv[idx] from the owning lane
            const double delta = rl_d(hij ? minvB : minvA, slj);

            if (rowUsedA) uA += delta;
            if (rowUsedB) uB += delta;
            if (usedA) vA -= delta; else minvA -= delta;
            if (usedB) vB -= delta; else minvB -= delta;

            j0 = idx;
            i0 = rl_i(hij ? pB : pA, slj);
            if (i0 == 0) break;

            usedA |= (j0 == jA);
            usedB |= (j0 == jB);
            rowUsedA |= (i0 == rA);
            rowUsedB |= (i0 == rB);
            {
                const bool hi = (i0 > 64);
                const int sl = (i0 - 1) & 63;
                rx = rl_f(hi ? rBx : rAx, sl);
                ry = rl_f(hi ? rBy : rAy, sl);
                rz = rl_f(hi ? rBz : rAz, sl);
                rw = rl_f(hi ? rBw : rAw, sl);
                rp = rl_f(hi ? peB : peA, sl);
                u0 = rl_d(hi ? uB : uA, sl);
            }
        }

        // augment along way[] chain — wave-uniform register walk
        int j = j0;
        while (j != 0) {
            int j1 = rl_i((j <= 64) ? wayA : wayB, (j - 1) & 63);
            int pnew;
            if (j1 == 0) pnew = i;  // p[0] = i
            else pnew = rl_i((j1 <= 64) ? pA : pB, (j1 - 1) & 63);
            if (jA == j) pA = pnew;
            if (jB == j) pB = pnew;
            j = j1;
        }
    }

    // SmoothL1 over matched pairs: target col t (0-based) matched to pred p[t+1]-1
    double acc = 0.0;
    if (lane < c) {
        float4 prow = s_row[pA - 1];
        acc += (double)(sl1f(prow.x - tAx) + sl1f(prow.y - tAy) + sl1f(prow.z - tAz));
    }
    if (lane + 64 < c) {
        float4 prow = s_row[pB - 1];
        acc += (double)(sl1f(prow.x - tBx) + sl1f(prow.y - tBy) + sl1f(prow.z - tBz));
    }
    for (int off = 1; off < 64; off <<= 1) acc += __shfl_xor(acc, off);
    if (lane == 0) ws_sl1[b] = acc;
}

// ---- BCE / finalize -------------------------------------------------------

__device__ __forceinline__ double bce_term(float p, float t) {
    float logp = fmaxf(logf(p), -100.0f);
    float logq = fmaxf(logf(1.0f - p), -100.0f);
    return (double)(-(t * logp + (1.0f - t) * logq));
}

__global__ __launch_bounds__(256) void bce_exist_kernel(
    const float* __restrict__ pe, const int* __restrict__ te, double* __restrict__ out)
{
    const int tid = threadIdx.x;
    double acc = 0.0;
    for (int i = tid; i < N_EX; i += 256)
        acc += bce_term(pe[i], (float)te[i]);
    for (int off = 1; off < 64; off <<= 1) acc += __shfl_xor(acc, off);
    __shared__ double s[4];
    if ((tid & 63) == 0) s[tid >> 6] = acc;
    __syncthreads();
    if (tid == 0) out[0] = s[0] + s[1] + s[2] + s[3];
}

__global__ __launch_bounds__(256) void bce_edge_kernel(
    const float* __restrict__ p, const float* __restrict__ t, double* __restrict__ out)
{
    const int tid = threadIdx.x;
    double acc = 0.0;
    for (int i = blockIdx.x * 256 + tid; i < N_EDGE; i += 256 * 256)
        acc += bce_term(p[i], t[i]);
    for (int off = 1; off < 64; off <<= 1) acc += __shfl_xor(acc, off);
    __shared__ double s[4];
    if ((tid & 63) == 0) s[tid >> 6] = acc;
    __syncthreads();
    if (tid == 0) out[blockIdx.x] = s[0] + s[1] + s[2] + s[3];
}

__global__ __launch_bounds__(64) void finalize_kernel(
    const double* __restrict__ ws, const int* __restrict__ counts, float* __restrict__ out)
{
    const int lane = threadIdx.x;
    double vsum = ws[lane];
    double csum = (double)counts[lane];
    double edsum = 0.0;
    for (int k = lane; k < 256; k += 64) edsum += ws[128 + k];
    for (int off = 1; off < 64; off <<= 1) {
        vsum  += __shfl_xor(vsum, off);
        csum  += __shfl_xor(csum, off);
        edsum += __shfl_xor(edsum, off);
    }
    if (lane == 0) {
        double vloss  = vsum / (3.0 * csum);
        double eloss  = ws[64] / (double)N_EX;
        double edloss = edsum / (double)N_EDGE;
        double total  = vloss + eloss + edloss;
        out[0] = (float)total;
        out[1] = (float)vloss;
        out[2] = (float)eloss;
        out[3] = (float)edloss;
    }
}

extern "C" void kernel_launch(void* const* d_in, const int* in_sizes, int n_in,
                              void* d_out, int out_size, void* d_ws, size_t ws_size,
                              hipStream_t stream) {
    const float* pv     = (const float*)d_in[0];
    const float* pe     = (const float*)d_in[1];
    const float* pedge  = (const float*)d_in[2];
    const float* tv     = (const float*)d_in[3];
    const int*   te     = (const int*)d_in[4];
    const float* elab   = (const float*)d_in[5];
    const int*   counts = (const int*)d_in[6];
    double* ws = (double*)d_ws;
    float* out = (float*)d_out;

    hipLaunchKernelGGL(hungarian_kernel, dim3(NB), dim3(64), 0, stream, pv, pe, tv, counts, ws);
    hipLaunchKernelGGL(bce_exist_kernel, dim3(1), dim3(256), 0, stream, pe, te, ws + 64);
    hipLaunchKernelGGL(bce_edge_kernel, dim3(256), dim3(256), 0, stream, pedge, elab, ws + 128);
    hipLaunchKernelGGL(finalize_kernel, dim3(1), dim3(64), 0, stream, ws, counts, out);
}

// Round 4
// 2687.467 us; speedup vs baseline: 2.5253x; 1.4698x over previous
//
#include <hip/hip_runtime.h>
#include <math.h>

#define NB 64
#define NV 128
#define NEDGE_PER 8128
#define N_EDGE (NB * NEDGE_PER)   // 520192
#define N_EX (NB * NV)            // 8192

// workspace layout (doubles):
// ws[0..63]    per-sample SmoothL1 sums
// ws[64]       existence BCE sum
// ws[128..383] edge BCE partials (256 blocks)

typedef unsigned long long u64;
typedef unsigned int uint2v __attribute__((ext_vector_type(2)));

__device__ __forceinline__ float sl1f(float d) {
    d = fabsf(d);
    return d < 1.0f ? 0.5f * d * d : d - 0.5f;
}

// ---- cross-lane helpers ---------------------------------------------------

template <int CTRL>
__device__ __forceinline__ int dpp_i(int x) {
    return __builtin_amdgcn_update_dpp(0, x, CTRL, 0xF, 0xF, true);
}
template <int CTRL>
__device__ __forceinline__ u64 dpp_u64(u64 x) {
    int lo = dpp_i<CTRL>((int)(unsigned)x);
    int hi = dpp_i<CTRL>((int)(unsigned)(x >> 32));
    return ((u64)(unsigned)hi << 32) | (unsigned)lo;
}

// Monotone u64 key of f64 with low 8 bits replaced by column idx (1..128).
// Exact ties break to lowest idx; near-ties (<2^-44 rel) may mis-select, but
// exact f64 values are re-read from the winning lane so duals stay ~exact,
// and any exact-optimal assignment matches the reference on real columns.
__device__ __forceinline__ u64 d2key(double x, int idx) {
    u64 b = (u64)__double_as_longlong(x);
    u64 m = (u64)(((long long)b) >> 63) | 0x8000000000000000ull;
    u64 k = b ^ m;
    return (k & ~0xFFull) | (u64)idx;
}
// ARR key: bit 8 = assigned-flag (prefer unassigned among ties), idx in 0..7.
__device__ __forceinline__ u64 d2key_arr(double x, bool assigned, int idx) {
    u64 b = (u64)__double_as_longlong(x);
    u64 m = (u64)(((long long)b) >> 63) | 0x8000000000000000ull;
    u64 k = b ^ m;
    return (k & ~0x1FFull) | (assigned ? 0x100ull : 0ull) | (u64)idx;
}

// 64-lane min over packed keys, broadcast to all lanes (validated r2/r3).
__device__ __forceinline__ u64 wave_minkey(u64 k) {
    { u64 o = dpp_u64<0xB1>(k);  if (o < k) k = o; }
    { u64 o = dpp_u64<0x4E>(k);  if (o < k) k = o; }
    { u64 o = dpp_u64<0x141>(k); if (o < k) k = o; }
    { u64 o = dpp_u64<0x140>(k); if (o < k) k = o; }
#if __has_builtin(__builtin_amdgcn_permlane16_swap)
    {
        unsigned klo = (unsigned)k, khi = (unsigned)(k >> 32);
        uint2v lo = __builtin_amdgcn_permlane16_swap(klo, klo, false, false);
        uint2v hi = __builtin_amdgcn_permlane16_swap(khi, khi, false, false);
        u64 o1 = ((u64)hi.x << 32) | lo.x;
        u64 o2 = ((u64)hi.y << 32) | lo.y;
        if (o1 < k) k = o1;
        if (o2 < k) k = o2;
    }
#else
    { u64 o = (u64)__shfl_xor((long long)k, 16); if (o < k) k = o; }
#endif
#if __has_builtin(__builtin_amdgcn_permlane32_swap)
    {
        unsigned klo = (unsigned)k, khi = (unsigned)(k >> 32);
        uint2v lo = __builtin_amdgcn_permlane32_swap(klo, klo, false, false);
        uint2v hi = __builtin_amdgcn_permlane32_swap(khi, khi, false, false);
        u64 o1 = ((u64)hi.x << 32) | lo.x;
        u64 o2 = ((u64)hi.y << 32) | lo.y;
        if (o1 < k) k = o1;
        if (o2 < k) k = o2;
    }
#else
    { u64 o = (u64)__shfl_xor((long long)k, 32); if (o < k) k = o; }
#endif
    return k;
}

// two-smallest merge: (k1<=k2) x (o1<=o2) -> two smallest of the 4 (all
// distinct column tags, so no duplicate-element hazard).
__device__ __forceinline__ void min2_merge(u64& k1, u64& k2, u64 o1, u64 o2) {
    if (k1 <= o1) {
        k2 = (k2 < o1) ? k2 : o1;
    } else {
        k2 = (o2 < k1) ? o2 : k1;
        k1 = o1;
    }
}
// 64-lane (min, second-min) over per-lane sorted pairs; broadcast result.
// xor16/xor32 via shfl (exact cross pair needed — permlane self-duplication
// would fake m2==m1 and stall ARR's dual progress).
__device__ __forceinline__ void wave_min2(u64& k1, u64& k2) {
    { u64 o1 = dpp_u64<0xB1>(k1),  o2 = dpp_u64<0xB1>(k2);  min2_merge(k1, k2, o1, o2); }
    { u64 o1 = dpp_u64<0x4E>(k1),  o2 = dpp_u64<0x4E>(k2);  min2_merge(k1, k2, o1, o2); }
    { u64 o1 = dpp_u64<0x141>(k1), o2 = dpp_u64<0x141>(k2); min2_merge(k1, k2, o1, o2); }
    { u64 o1 = dpp_u64<0x140>(k1), o2 = dpp_u64<0x140>(k2); min2_merge(k1, k2, o1, o2); }
    { u64 o1 = (u64)__shfl_xor((long long)k1, 16), o2 = (u64)__shfl_xor((long long)k2, 16); min2_merge(k1, k2, o1, o2); }
    { u64 o1 = (u64)__shfl_xor((long long)k1, 32), o2 = (u64)__shfl_xor((long long)k2, 32); min2_merge(k1, k2, o1, o2); }
}

__device__ __forceinline__ int rl_i(int v, int sl) {
    return __builtin_amdgcn_readlane(v, sl);
}
__device__ __forceinline__ float rl_f(float v, int sl) {
    return __int_as_float(__builtin_amdgcn_readlane(__float_as_int(v), sl));
}
__device__ __forceinline__ double rl_d(double v, int sl) {
    return __hiloint2double(__builtin_amdgcn_readlane(__double2hiint(v), sl),
                            __builtin_amdgcn_readlane(__double2loint(v), sl));
}

// ---- Hungarian: LAPJV-style (colred + ARR + augment), one wave/sample -----

__global__ __launch_bounds__(64, 1) void hungarian_kernel(
    const float* __restrict__ pv,     // [B,V,3]
    const float* __restrict__ pe,     // [B,V]
    const float* __restrict__ tv,     // [B,V,3]
    const int*   __restrict__ counts, // [B]
    double* __restrict__ ws_sl1)      // [B]
{
    const int b = blockIdx.x;
    const int lane = threadIdx.x;
    const int c = counts[b];

    __shared__ float4 s_row[NV];
    __shared__ float  s_pe[NV];
    __shared__ int    s_colpick[NV];
    __shared__ int    s_rowacc[NV];

    const float* pvb = pv + (size_t)b * NV * 3;
    const float* peb = pe + (size_t)b * NV;
    const float* tvb = tv + (size_t)b * NV * 3;

    // lane owns rows/cols (1-based): rA=jA=lane+1, rB=jB=lane+65
    float rAx = pvb[lane * 3 + 0], rAy = pvb[lane * 3 + 1], rAz = pvb[lane * 3 + 2];
    float rBx = pvb[(lane + 64) * 3 + 0], rBy = pvb[(lane + 64) * 3 + 1], rBz = pvb[(lane + 64) * 3 + 2];
    float peA = peb[lane], peB = peb[lane + 64];
    float rAw = fabsf(peA - 1.0f), rBw = fabsf(peB - 1.0f);
    s_row[lane]      = make_float4(rAx, rAy, rAz, rAw);
    s_row[lane + 64] = make_float4(rBx, rBy, rBz, rBw);
    s_pe[lane]       = peA;
    s_pe[lane + 64]  = peB;

    const float tAx = tvb[lane * 3 + 0], tAy = tvb[lane * 3 + 1], tAz = tvb[lane * 3 + 2];
    const float tBx = tvb[(lane + 64) * 3 + 0], tBy = tvb[(lane + 64) * 3 + 1], tBz = tvb[(lane + 64) * 3 + 2];

    const int jA = lane + 1, jB = lane + 65;
    const int rA = lane + 1, rB = lane + 65;
    const bool realA = (jA <= c), realB = (jB <= c);

    __syncthreads();

    // ---- Phase A: column reduction (v[j] = min_i C[i][j], f32-exact) ------
    float bestA = 3.4e38f, bestB = 3.4e38f;
    int bestAr = 1, bestBr = 1;
    #pragma unroll 4
    for (int r = 0; r < NV; ++r) {
        float4 row = s_row[r];
        float per = s_pe[r];
        float cA = realA ? (((fabsf(row.x - tAx) + fabsf(row.y - tAy)) + fabsf(row.z - tAz)) + row.w) : per;
        float cB = realB ? (((fabsf(row.x - tBx) + fabsf(row.y - tBy)) + fabsf(row.z - tBz)) + row.w) : per;
        if (cA < bestA) { bestA = cA; bestAr = r + 1; }
        if (cB < bestB) { bestB = cB; bestBr = r + 1; }
    }
    double vA = (double)bestA, vB = (double)bestB;  // column potentials
    double uA = 0.0, uB = 0.0;                      // row potentials

    // greedy tight assignment: column's argmin row accepts its lowest column
    s_colpick[jA - 1] = bestAr;
    s_colpick[jB - 1] = bestBr;
    __syncthreads();
    int xA = 0, xB = 0;                             // x[row] = col (0 free)
    #pragma unroll 4
    for (int j = 0; j < NV; ++j) {
        int pick = s_colpick[j];
        if (xA == 0 && pick == rA) xA = j + 1;
        if (xB == 0 && pick == rB) xB = j + 1;
    }
    s_rowacc[rA - 1] = xA;
    s_rowacc[rB - 1] = xB;
    __syncthreads();
    int pA = (s_rowacc[bestAr - 1] == jA) ? bestAr : 0;  // y[col] = row (0 free)
    int pB = (s_rowacc[bestBr - 1] == jB) ? bestBr : 0;

    u64 mA = __ballot(xA == 0);   // bit l: row l+1 unassigned
    u64 mB = __ballot(xB == 0);   // bit l: row l+65 unassigned

    // ---- Phase B: augmenting row reduction (auction-like, exact duals) ----
    int steps = 0;
    while ((mA | mB) != 0ull && steps < 600) {
        ++steps;
        const int i0 = mA ? (__builtin_ctzll(mA) + 1) : (__builtin_ctzll(mB) + 65);
        const bool hi = (i0 > 64);
        const int sl = (i0 - 1) & 63;
        const float rx = rl_f(hi ? rBx : rAx, sl);
        const float ry = rl_f(hi ? rBy : rAy, sl);
        const float rz = rl_f(hi ? rBz : rAz, sl);
        const float rw = rl_f(hi ? rBw : rAw, sl);
        const float rp = rl_f(hi ? peB : peA, sl);

        const float cfA = realA ? (((fabsf(rx - tAx) + fabsf(ry - tAy)) + fabsf(rz - tAz)) + rw) : rp;
        const float cfB = realB ? (((fabsf(rx - tBx) + fabsf(ry - tBy)) + fabsf(rz - tBz)) + rw) : rp;
        const double rjA = (double)cfA - vA;   // reduced cost sans u
        const double rjB = (double)cfB - vB;

        u64 k1 = d2key_arr(rjA, pA != 0, jA);
        u64 k2 = d2key_arr(rjB, pB != 0, jB);
        if (k2 < k1) { u64 t = k1; k1 = k2; k2 = t; }
        wave_min2(k1, k2);

        const int j1 = (int)(__builtin_amdgcn_readfirstlane((unsigned)k1) & 0xFFu);
        const int j2 = (int)(__builtin_amdgcn_readfirstlane((unsigned)k2) & 0xFFu);
        const bool h1 = (j1 > 64); const int s1 = (j1 - 1) & 63;
        const bool h2 = (j2 > 64); const int s2 = (j2 - 1) & 63;
        const double m1 = rl_d(h1 ? rjB : rjA, s1);
        const double m2 = rl_d(h2 ? rjB : rjA, s2);
        const int kdisp = rl_i(h1 ? pB : pA, s1);   // row displaced from j1

        // dual update keeps feasibility: r'(i0,j1)=m2 (tight), others >= m2
        if (jA == j1) { vA -= (m2 - m1); pA = i0; }
        if (jB == j1) { vB -= (m2 - m1); pB = i0; }
        if (rA == i0) { uA = m2; xA = j1; }
        if (rB == i0) { uB = m2; xB = j1; }
        if (hi) mB &= ~(1ull << sl); else mA &= ~(1ull << sl);
        if (kdisp != 0) {
            if (rA == kdisp) xA = 0;
            if (rB == kdisp) xB = 0;
            if (kdisp > 64) mB |= (1ull << (kdisp - 65)); else mA |= (1ull << (kdisp - 1));
        }
    }

    // ---- Phase C: shortest augmenting paths for remaining rows ------------
    const double INF = 1e18;
    while ((mA | mB) != 0ull) {
        const int f = mA ? (__builtin_ctzll(mA) + 1) : (__builtin_ctzll(mB) + 65);
        if (f <= 64) mA &= ~(1ull << (f - 1)); else mB &= ~(1ull << (f - 65));

        double minvA = INF, minvB = INF;
        bool usedA = false, usedB = false;
        bool rowUsedA = (rA == f), rowUsedB = (rB == f);
        int wayA = 0, wayB = 0;
        int j0 = 0;
        int i0 = f;                  // p[0] = f

        float rx, ry, rz, rw, rp; double u0;
        {
            const bool hi = (i0 > 64);
            const int sl = (i0 - 1) & 63;
            rx = rl_f(hi ? rBx : rAx, sl);
            ry = rl_f(hi ? rBy : rAy, sl);
            rz = rl_f(hi ? rBz : rAz, sl);
            rw = rl_f(hi ? rBw : rAw, sl);
            rp = rl_f(hi ? peB : peA, sl);
            u0 = rl_d(hi ? uB : uA, sl);
        }

        for (;;) {
            if (!usedA) {
                float cf = realA ? (((fabsf(rx - tAx) + fabsf(ry - tAy)) + fabsf(rz - tAz)) + rw) : rp;
                double cur = ((double)cf - u0) - vA;
                if (cur < minvA) { minvA = cur; wayA = j0; }
            }
            if (!usedB) {
                float cf = realB ? (((fabsf(rx - tBx) + fabsf(ry - tBy)) + fabsf(rz - tBz)) + rw) : rp;
                double cur = ((double)cf - u0) - vB;
                if (cur < minvB) { minvB = cur; wayB = j0; }
            }

            u64 kA = usedA ? ~0ull : d2key(minvA, jA);
            u64 kB = usedB ? ~0ull : d2key(minvB, jB);
            u64 k = (kB < kA) ? kB : kA;
            k = wave_minkey(k);

            const int idx = (int)(__builtin_amdgcn_readfirstlane((unsigned)k) & 0xFFu);
            const bool hij = (idx > 64);
            const int slj = (idx - 1) & 63;
            const double delta = rl_d(hij ? minvB : minvA, slj);

            if (rowUsedA) uA += delta;
            if (rowUsedB) uB += delta;
            if (usedA) vA -= delta; else minvA -= delta;
            if (usedB) vB -= delta; else minvB -= delta;

            j0 = idx;
            i0 = rl_i(hij ? pB : pA, slj);
            if (i0 == 0) break;

            usedA |= (j0 == jA);
            usedB |= (j0 == jB);
            rowUsedA |= (i0 == rA);
            rowUsedB |= (i0 == rB);
            {
                const bool hi = (i0 > 64);
                const int sl = (i0 - 1) & 63;
                rx = rl_f(hi ? rBx : rAx, sl);
                ry = rl_f(hi ? rBy : rAy, sl);
                rz = rl_f(hi ? rBz : rAz, sl);
                rw = rl_f(hi ? rBw : rAw, sl);
                rp = rl_f(hi ? peB : peA, sl);
                u0 = rl_d(hi ? uB : uA, sl);
            }
        }

        // augment along way[] chain
        int j = j0;
        while (j != 0) {
            int j1 = rl_i((j <= 64) ? wayA : wayB, (j - 1) & 63);
            int pnew = (j1 == 0) ? f : rl_i((j1 <= 64) ? pA : pB, (j1 - 1) & 63);
            if (jA == j) pA = pnew;
            if (jB == j) pB = pnew;
            j = j1;
        }
    }

    // ---- SmoothL1 over matched pairs (cols < c) ---------------------------
    double acc = 0.0;
    if (lane < c) {
        float4 prow = s_row[pA - 1];
        acc += (double)(sl1f(prow.x - tAx) + sl1f(prow.y - tAy) + sl1f(prow.z - tAz));
    }
    if (lane + 64 < c) {
        float4 prow = s_row[pB - 1];
        acc += (double)(sl1f(prow.x - tBx) + sl1f(prow.y - tBy) + sl1f(prow.z - tBz));
    }
    for (int off = 1; off < 64; off <<= 1) acc += __shfl_xor(acc, off);
    if (lane == 0) ws_sl1[b] = acc;
}

// ---- BCE / finalize -------------------------------------------------------

__device__ __forceinline__ double bce_term(float p, float t) {
    float logp = fmaxf(logf(p), -100.0f);
    float logq = fmaxf(logf(1.0f - p), -100.0f);
    return (double)(-(t * logp + (1.0f - t) * logq));
}

__global__ __launch_bounds__(256) void bce_exist_kernel(
    const float* __restrict__ pe, const int* __restrict__ te, double* __restrict__ out)
{
    const int tid = threadIdx.x;
    double acc = 0.0;
    for (int i = tid; i < N_EX; i += 256)
        acc += bce_term(pe[i], (float)te[i]);
    for (int off = 1; off < 64; off <<= 1) acc += __shfl_xor(acc, off);
    __shared__ double s[4];
    if ((tid & 63) == 0) s[tid >> 6] = acc;
    __syncthreads();
    if (tid == 0) out[0] = s[0] + s[1] + s[2] + s[3];
}

__global__ __launch_bounds__(256) void bce_edge_kernel(
    const float* __restrict__ p, const float* __restrict__ t, double* __restrict__ out)
{
    const int tid = threadIdx.x;
    double acc = 0.0;
    for (int i = blockIdx.x * 256 + tid; i < N_EDGE; i += 256 * 256)
        acc += bce_term(p[i], t[i]);
    for (int off = 1; off < 64; off <<= 1) acc += __shfl_xor(acc, off);
    __shared__ double s[4];
    if ((tid & 63) == 0) s[tid >> 6] = acc;
    __syncthreads();
    if (tid == 0) out[blockIdx.x] = s[0] + s[1] + s[2] + s[3];
}

__global__ __launch_bounds__(64) void finalize_kernel(
    const double* __restrict__ ws, const int* __restrict__ counts, float* __restrict__ out)
{
    const int lane = threadIdx.x;
    double vsum = ws[lane];
    double csum = (double)counts[lane];
    double edsum = 0.0;
    for (int k = lane; k < 256; k += 64) edsum += ws[128 + k];
    for (int off = 1; off < 64; off <<= 1) {
        vsum  += __shfl_xor(vsum, off);
        csum  += __shfl_xor(csum, off);
        edsum += __shfl_xor(edsum, off);
    }
    if (lane == 0) {
        double vloss  = vsum / (3.0 * csum);
        double eloss  = ws[64] / (double)N_EX;
        double edloss = edsum / (double)N_EDGE;
        double total  = vloss + eloss + edloss;
        out[0] = (float)total;
        out[1] = (float)vloss;
        out[2] = (float)eloss;
        out[3] = (float)edloss;
    }
}

extern "C" void kernel_launch(void* const* d_in, const int* in_sizes, int n_in,
                              void* d_out, int out_size, void* d_ws, size_t ws_size,
                              hipStream_t stream) {
    const float* pv     = (const float*)d_in[0];
    const float* pe     = (const float*)d_in[1];
    const float* pedge  = (const float*)d_in[2];
    const float* tv     = (const float*)d_in[3];
    const int*   te     = (const int*)d_in[4];
    const float* elab   = (const float*)d_in[5];
    const int*   counts = (const int*)d_in[6];
    double* ws = (double*)d_ws;
    float* out = (float*)d_out;

    hipLaunchKernelGGL(hungarian_kernel, dim3(NB), dim3(64), 0, stream, pv, pe, tv, counts, ws);
    hipLaunchKernelGGL(bce_exist_kernel, dim3(1), dim3(256), 0, stream, pe, te, ws + 64);
    hipLaunchKernelGGL(bce_edge_kernel, dim3(256), dim3(256), 0, stream, pedge, elab, ws + 128);
    hipLaunchKernelGGL(finalize_kernel, dim3(1), dim3(64), 0, stream, ws, counts, out);
}

// Round 5
// 1352.431 us; speedup vs baseline: 5.0181x; 1.9871x over previous
//
#include <hip/hip_runtime.h>
#include <math.h>

#define NB 64
#define NV 128
#define NEDGE_PER 8128
#define N_EDGE (NB * NEDGE_PER)   // 520192
#define N_EX (NB * NV)            // 8192

// workspace layout (doubles):
// ws[0..63]    per-sample SmoothL1 sums
// ws[64]       existence BCE sum
// ws[128..383] edge BCE partials (256 blocks)

typedef unsigned long long u64;
typedef unsigned int uint2v __attribute__((ext_vector_type(2)));

__device__ __forceinline__ float sl1f(float d) {
    d = fabsf(d);
    return d < 1.0f ? 0.5f * d * d : d - 0.5f;
}
__device__ __forceinline__ unsigned umin2(unsigned a, unsigned b) { return a < b ? a : b; }

// ---- cross-lane helpers ---------------------------------------------------

template <int CTRL>
__device__ __forceinline__ int dpp_i(int x) {
    return __builtin_amdgcn_update_dpp(0, x, CTRL, 0xF, 0xF, true);
}

// Monotone u32 key of f32; low 8 bits = column idx (1..128). Quantizes the
// value to ~2^-15 relative for ordering; exact ties (and sub-quantum near-
// ties) break to lowest idx. Exact f32 values are re-read from the winning
// lane, so duals stay accurate; sub-quantum mis-picks perturb the match only
// among near-optimal alternates (loss impact ~1e-4 << 4.19e-2 threshold).
__device__ __forceinline__ unsigned f2key(float x, int idx) {
    unsigned b = __float_as_uint(x);
    unsigned m = (unsigned)(((int)b) >> 31) | 0x80000000u;
    return ((b ^ m) & ~0xFFu) | (unsigned)idx;
}
// ARR key: bit 8 = assigned-flag (prefer unassigned among ties).
__device__ __forceinline__ unsigned f2key_arr(float x, bool assigned, int idx) {
    unsigned b = __float_as_uint(x);
    unsigned m = (unsigned)(((int)b) >> 31) | 0x80000000u;
    return ((b ^ m) & ~0x1FFu) | (assigned ? 0x100u : 0u) | (unsigned)idx;
}

// 64-lane min over 32-bit packed keys, broadcast to all lanes.
__device__ __forceinline__ unsigned wave_minkey32(unsigned k) {
    { unsigned o = (unsigned)dpp_i<0xB1>((int)k);  k = umin2(k, o); }  // quad xor1
    { unsigned o = (unsigned)dpp_i<0x4E>((int)k);  k = umin2(k, o); }  // quad xor2
    { unsigned o = (unsigned)dpp_i<0x141>((int)k); k = umin2(k, o); }  // half_mirror (^4)
    { unsigned o = (unsigned)dpp_i<0x140>((int)k); k = umin2(k, o); }  // row_mirror (^8)
#if __has_builtin(__builtin_amdgcn_permlane16_swap)
    { uint2v r = __builtin_amdgcn_permlane16_swap(k, k, false, false);
      k = umin2(k, umin2(r.x, r.y)); }
#else
    { k = umin2(k, (unsigned)__shfl_xor((int)k, 16)); }
#endif
#if __has_builtin(__builtin_amdgcn_permlane32_swap)
    { uint2v r = __builtin_amdgcn_permlane32_swap(k, k, false, false);
      k = umin2(k, umin2(r.x, r.y)); }
#else
    { k = umin2(k, (unsigned)__shfl_xor((int)k, 32)); }
#endif
    return k;
}

// two-smallest merge; requires k1<=k2 and o1<=o2 (self-pair merge harmless).
__device__ __forceinline__ void min2m(unsigned& k1, unsigned& k2, unsigned o1, unsigned o2) {
    if (k1 <= o1) {
        k2 = umin2(k2, o1);
    } else {
        k2 = umin2(o2, k1);
        k1 = o1;
    }
}
// 64-lane (min, 2nd-min) over per-lane sorted pairs; broadcast. Permlane swap
// orientation ambiguity is harmless: both output pairings are merged and a
// self-merge is a no-op.
__device__ __forceinline__ void wave_min2_32(unsigned& k1, unsigned& k2) {
    { unsigned o1 = (unsigned)dpp_i<0xB1>((int)k1),  o2 = (unsigned)dpp_i<0xB1>((int)k2);  min2m(k1, k2, o1, o2); }
    { unsigned o1 = (unsigned)dpp_i<0x4E>((int)k1),  o2 = (unsigned)dpp_i<0x4E>((int)k2);  min2m(k1, k2, o1, o2); }
    { unsigned o1 = (unsigned)dpp_i<0x141>((int)k1), o2 = (unsigned)dpp_i<0x141>((int)k2); min2m(k1, k2, o1, o2); }
    { unsigned o1 = (unsigned)dpp_i<0x140>((int)k1), o2 = (unsigned)dpp_i<0x140>((int)k2); min2m(k1, k2, o1, o2); }
#if __has_builtin(__builtin_amdgcn_permlane16_swap)
    { uint2v r1 = __builtin_amdgcn_permlane16_swap(k1, k1, false, false);
      uint2v r2 = __builtin_amdgcn_permlane16_swap(k2, k2, false, false);
      min2m(k1, k2, r1.x, r2.x); min2m(k1, k2, r1.y, r2.y); }
#else
    { unsigned o1 = (unsigned)__shfl_xor((int)k1, 16), o2 = (unsigned)__shfl_xor((int)k2, 16); min2m(k1, k2, o1, o2); }
#endif
#if __has_builtin(__builtin_amdgcn_permlane32_swap)
    { uint2v r1 = __builtin_amdgcn_permlane32_swap(k1, k1, false, false);
      uint2v r2 = __builtin_amdgcn_permlane32_swap(k2, k2, false, false);
      min2m(k1, k2, r1.x, r2.x); min2m(k1, k2, r1.y, r2.y); }
#else
    { unsigned o1 = (unsigned)__shfl_xor((int)k1, 32), o2 = (unsigned)__shfl_xor((int)k2, 32); min2m(k1, k2, o1, o2); }
#endif
}

__device__ __forceinline__ int rl_i(int v, int sl) {
    return __builtin_amdgcn_readlane(v, sl);
}
__device__ __forceinline__ float rl_f(float v, int sl) {
    return __int_as_float(__builtin_amdgcn_readlane(__float_as_int(v), sl));
}

// ---- Hungarian: LDS cost matrix + colred + ARR(tie-skip) + augment --------

__global__ __launch_bounds__(64, 1) void hungarian_kernel(
    const float* __restrict__ pv,     // [B,V,3]
    const float* __restrict__ pe,     // [B,V]
    const float* __restrict__ tv,     // [B,V,3]
    const int*   __restrict__ counts, // [B]
    double* __restrict__ ws_sl1)      // [B]
{
    const int b = blockIdx.x;
    const int lane = threadIdx.x;
    const int c = counts[b];

    __shared__ float2 s_cost[NV * 64];   // [row][lane] = (C[row][lane+1], C[row][lane+65])
    __shared__ float4 s_row[NV];
    __shared__ float  s_pe[NV];
    __shared__ int    s_colpick[NV];
    __shared__ int    s_rowacc[NV];

    const float* pvb = pv + (size_t)b * NV * 3;
    const float* peb = pe + (size_t)b * NV;
    const float* tvb = tv + (size_t)b * NV * 3;

    // lane owns rows/cols (1-based): rA=jA=lane+1, rB=jB=lane+65
    {
        float x0 = pvb[lane * 3 + 0], y0 = pvb[lane * 3 + 1], z0 = pvb[lane * 3 + 2];
        float x1 = pvb[(lane + 64) * 3 + 0], y1 = pvb[(lane + 64) * 3 + 1], z1 = pvb[(lane + 64) * 3 + 2];
        float e0 = peb[lane], e1 = peb[lane + 64];
        s_row[lane]      = make_float4(x0, y0, z0, fabsf(e0 - 1.0f));
        s_row[lane + 64] = make_float4(x1, y1, z1, fabsf(e1 - 1.0f));
        s_pe[lane]       = e0;
        s_pe[lane + 64]  = e1;
    }
    const float tAx = tvb[lane * 3 + 0], tAy = tvb[lane * 3 + 1], tAz = tvb[lane * 3 + 2];
    const float tBx = tvb[(lane + 64) * 3 + 0], tBy = tvb[(lane + 64) * 3 + 1], tBz = tvb[(lane + 64) * 3 + 2];

    const int jA = lane + 1, jB = lane + 65;
    const int rA = lane + 1, rB = lane + 65;
    const bool realA = (jA <= c), realB = (jB <= c);

    __syncthreads();

    // ---- Phase 0: build cost matrix (f32-exact, reference op order) -------
    #pragma unroll 4
    for (int r = 0; r < NV; ++r) {
        float4 row = s_row[r];
        float per = s_pe[r];
        float cA = realA ? (((fabsf(row.x - tAx) + fabsf(row.y - tAy)) + fabsf(row.z - tAz)) + row.w) : per;
        float cB = realB ? (((fabsf(row.x - tBx) + fabsf(row.y - tBy)) + fabsf(row.z - tBz)) + row.w) : per;
        s_cost[r * 64 + lane] = make_float2(cA, cB);
    }
    __syncthreads();

    // ---- Phase A: column reduction + greedy tight assignment --------------
    float bestA = 3.4e38f, bestB = 3.4e38f;
    int bestAr = 1, bestBr = 1;
    #pragma unroll 4
    for (int r = 0; r < NV; ++r) {
        float2 cc = s_cost[r * 64 + lane];
        if (cc.x < bestA) { bestA = cc.x; bestAr = r + 1; }
        if (cc.y < bestB) { bestB = cc.y; bestBr = r + 1; }
    }
    float vA = bestA, vB = bestB;   // column potentials
    float uA = 0.0f, uB = 0.0f;     // row potentials

    s_colpick[jA - 1] = bestAr;
    s_colpick[jB - 1] = bestBr;
    __syncthreads();
    int xA = 0, xB = 0;             // x[row] = col (0 free)
    #pragma unroll 4
    for (int j = 0; j < NV; ++j) {
        int pick = s_colpick[j];
        if (xA == 0 && pick == rA) xA = j + 1;
        if (xB == 0 && pick == rB) xB = j + 1;
    }
    s_rowacc[rA - 1] = xA;
    s_rowacc[rB - 1] = xB;
    __syncthreads();
    int pA = (s_rowacc[bestAr - 1] == jA) ? bestAr : 0;  // y[col] = row (0 free)
    int pB = (s_rowacc[bestBr - 1] == jB) ? bestBr : 0;

    u64 mA = __ballot(xA == 0);   // bit l: row l+1 unassigned
    u64 mB = __ballot(xB == 0);   // bit l: row l+65 unassigned
    u64 dA = 0ull, dB = 0ull;     // deferred (tie-skipped) rows -> Phase C

    // ---- Phase B: augmenting row reduction (tie-skip, clamped duals) ------
    int steps = 0;
    while ((mA | mB) != 0ull && steps < 600) {
        ++steps;
        const int i0 = mA ? (__builtin_ctzll(mA) + 1) : (__builtin_ctzll(mB) + 65);
        const bool hi = (i0 > 64);
        const int sl = (i0 - 1) & 63;

        float2 cc = s_cost[(i0 - 1) * 64 + lane];
        const float rjA = cc.x - vA;
        const float rjB = cc.y - vB;

        unsigned k1 = f2key_arr(rjA, pA != 0, jA);
        unsigned k2 = f2key_arr(rjB, pB != 0, jB);
        if (k2 < k1) { unsigned t = k1; k1 = k2; k2 = t; }
        wave_min2_32(k1, k2);

        const int j1 = (int)(__builtin_amdgcn_readfirstlane(k1) & 0xFFu);
        const int j2 = (int)(__builtin_amdgcn_readfirstlane(k2) & 0xFFu);
        const bool h1 = (j1 > 64); const int s1 = (j1 - 1) & 63;
        const bool h2 = (j2 > 64); const int s2 = (j2 - 1) & 63;
        const float m1 = rl_f(h1 ? rjB : rjA, s1);
        const float m2 = rl_f(h2 ? rjB : rjA, s2);
        const int kdisp = rl_i(h1 ? pB : pA, s1);   // row currently on j1

        if (hi) mB &= ~(1ull << sl); else mA &= ~(1ull << sl);

        if (kdisp != 0 && !(m2 > m1)) {
            // tied displacement: no dual progress possible; defer to Phase C
            if (hi) dB |= (1ull << sl); else dA |= (1ull << sl);
            continue;
        }
        const float dlt = fmaxf(m2 - m1, 0.0f);
        if (jA == j1) { vA -= dlt; pA = i0; }
        if (jB == j1) { vB -= dlt; pB = i0; }
        if (rA == i0) { uA = m2; xA = j1; }
        if (rB == i0) { uB = m2; xB = j1; }
        if (kdisp != 0) {
            if (rA == kdisp) xA = 0;
            if (rB == kdisp) xB = 0;
            if (kdisp > 64) mB |= (1ull << (kdisp - 65)); else mA |= (1ull << (kdisp - 1));
        }
    }
    mA |= dA;
    mB |= dB;

    // ---- Phase C: shortest augmenting paths for remaining rows ------------
    const float INF = 3.4e38f;
    while ((mA | mB) != 0ull) {
        const int f = mA ? (__builtin_ctzll(mA) + 1) : (__builtin_ctzll(mB) + 65);
        if (f <= 64) mA &= ~(1ull << (f - 1)); else mB &= ~(1ull << (f - 65));

        float minvA = INF, minvB = INF;
        bool usedA = false, usedB = false;
        bool rowUsedA = (rA == f), rowUsedB = (rB == f);
        int wayA = 0, wayB = 0;
        int j0 = 0;
        int i0 = f;                  // p[0] = f

        float u0;
        {
            const bool hi = (i0 > 64);
            const int sl = (i0 - 1) & 63;
            u0 = rl_f(hi ? uB : uA, sl);
        }
        float2 cc = s_cost[(i0 - 1) * 64 + lane];

        for (;;) {
            if (!usedA) {
                float cur = (cc.x - u0) - vA;
                if (cur < minvA) { minvA = cur; wayA = j0; }
            }
            if (!usedB) {
                float cur = (cc.y - u0) - vB;
                if (cur < minvB) { minvB = cur; wayB = j0; }
            }

            unsigned kA = usedA ? 0xFFFFFFFFu : f2key(minvA, jA);
            unsigned kB = usedB ? 0xFFFFFFFFu : f2key(minvB, jB);
            unsigned k = umin2(kA, kB);
            k = wave_minkey32(k);

            const int idx = (int)(__builtin_amdgcn_readfirstlane(k) & 0xFFu);
            const bool hij = (idx > 64);
            const int slj = (idx - 1) & 63;
            const float delta = rl_f(hij ? minvB : minvA, slj);

            if (rowUsedA) uA += delta;
            if (rowUsedB) uB += delta;
            if (usedA) vA -= delta; else minvA -= delta;
            if (usedB) vB -= delta; else minvB -= delta;

            j0 = idx;
            i0 = rl_i(hij ? pB : pA, slj);
            if (i0 == 0) break;

            usedA |= (j0 == jA);
            usedB |= (j0 == jB);
            rowUsedA |= (i0 == rA);
            rowUsedB |= (i0 == rB);
            {
                const bool hi = (i0 > 64);
                const int sl = (i0 - 1) & 63;
                u0 = rl_f(hi ? uB : uA, sl);
            }
            cc = s_cost[(i0 - 1) * 64 + lane];
        }

        // augment along way[] chain
        int j = j0;
        while (j != 0) {
            int j1 = rl_i((j <= 64) ? wayA : wayB, (j - 1) & 63);
            int pnew = (j1 == 0) ? f : rl_i((j1 <= 64) ? pA : pB, (j1 - 1) & 63);
            if (jA == j) pA = pnew;
            if (jB == j) pB = pnew;
            j = j1;
        }
    }

    // ---- SmoothL1 over matched pairs (cols < c) ---------------------------
    double acc = 0.0;
    if (lane < c) {
        float4 prow = s_row[pA - 1];
        acc += (double)(sl1f(prow.x - tAx) + sl1f(prow.y - tAy) + sl1f(prow.z - tAz));
    }
    if (lane + 64 < c) {
        float4 prow = s_row[pB - 1];
        acc += (double)(sl1f(prow.x - tBx) + sl1f(prow.y - tBy) + sl1f(prow.z - tBz));
    }
    for (int off = 1; off < 64; off <<= 1) acc += __shfl_xor(acc, off);
    if (lane == 0) ws_sl1[b] = acc;
}

// ---- BCE / finalize -------------------------------------------------------

__device__ __forceinline__ double bce_term(float p, float t) {
    float logp = fmaxf(logf(p), -100.0f);
    float logq = fmaxf(logf(1.0f - p), -100.0f);
    return (double)(-(t * logp + (1.0f - t) * logq));
}

__global__ __launch_bounds__(256) void bce_exist_kernel(
    const float* __restrict__ pe, const int* __restrict__ te, double* __restrict__ out)
{
    const int tid = threadIdx.x;
    double acc = 0.0;
    for (int i = tid; i < N_EX; i += 256)
        acc += bce_term(pe[i], (float)te[i]);
    for (int off = 1; off < 64; off <<= 1) acc += __shfl_xor(acc, off);
    __shared__ double s[4];
    if ((tid & 63) == 0) s[tid >> 6] = acc;
    __syncthreads();
    if (tid == 0) out[0] = s[0] + s[1] + s[2] + s[3];
}

__global__ __launch_bounds__(256) void bce_edge_kernel(
    const float* __restrict__ p, const float* __restrict__ t, double* __restrict__ out)
{
    const int tid = threadIdx.x;
    double acc = 0.0;
    for (int i = blockIdx.x * 256 + tid; i < N_EDGE; i += 256 * 256)
        acc += bce_term(p[i], t[i]);
    for (int off = 1; off < 64; off <<= 1) acc += __shfl_xor(acc, off);
    __shared__ double s[4];
    if ((tid & 63) == 0) s[tid >> 6] = acc;
    __syncthreads();
    if (tid == 0) out[blockIdx.x] = s[0] + s[1] + s[2] + s[3];
}

__global__ __launch_bounds__(64) void finalize_kernel(
    const double* __restrict__ ws, const int* __restrict__ counts, float* __restrict__ out)
{
    const int lane = threadIdx.x;
    double vsum = ws[lane];
    double csum = (double)counts[lane];
    double edsum = 0.0;
    for (int k = lane; k < 256; k += 64) edsum += ws[128 + k];
    for (int off = 1; off < 64; off <<= 1) {
        vsum  += __shfl_xor(vsum, off);
        csum  += __shfl_xor(csum, off);
        edsum += __shfl_xor(edsum, off);
    }
    if (lane == 0) {
        double vloss  = vsum / (3.0 * csum);
        double eloss  = ws[64] / (double)N_EX;
        double edloss = edsum / (double)N_EDGE;
        double total  = vloss + eloss + edloss;
        out[0] = (float)total;
        out[1] = (float)vloss;
        out[2] = (float)eloss;
        out[3] = (float)edloss;
    }
}

extern "C" void kernel_launch(void* const* d_in, const int* in_sizes, int n_in,
                              void* d_out, int out_size, void* d_ws, size_t ws_size,
                              hipStream_t stream) {
    const float* pv     = (const float*)d_in[0];
    const float* pe     = (const float*)d_in[1];
    const float* pedge  = (const float*)d_in[2];
    const float* tv     = (const float*)d_in[3];
    const int*   te     = (const int*)d_in[4];
    const float* elab   = (const float*)d_in[5];
    const int*   counts = (const int*)d_in[6];
    double* ws = (double*)d_ws;
    float* out = (float*)d_out;

    hipLaunchKernelGGL(hungarian_kernel, dim3(NB), dim3(64), 0, stream, pv, pe, tv, counts, ws);
    hipLaunchKernelGGL(bce_exist_kernel, dim3(1), dim3(256), 0, stream, pe, te, ws + 64);
    hipLaunchKernelGGL(bce_edge_kernel, dim3(256), dim3(256), 0, stream, pedge, elab, ws + 128);
    hipLaunchKernelGGL(finalize_kernel, dim3(1), dim3(64), 0, stream, ws, counts, out);
}

// Round 6
// 1300.602 us; speedup vs baseline: 5.2181x; 1.0398x over previous
//
#include <hip/hip_runtime.h>
#include <math.h>

#define NB 64
#define NV 128
#define NEDGE_PER 8128
#define N_EDGE (NB * NEDGE_PER)   // 520192
#define N_EX (NB * NV)            // 8192

// workspace layout (doubles):
// ws[0..63]    per-sample SmoothL1 sums
// ws[64]       existence BCE sum
// ws[128..383] edge BCE partials (256 blocks)

typedef unsigned long long u64;
typedef unsigned int uint2v __attribute__((ext_vector_type(2)));

__device__ __forceinline__ float sl1f(float d) {
    d = fabsf(d);
    return d < 1.0f ? 0.5f * d * d : d - 0.5f;
}
__device__ __forceinline__ unsigned umin2(unsigned a, unsigned b) { return a < b ? a : b; }

// ---- cross-lane helpers ---------------------------------------------------

template <int CTRL>
__device__ __forceinline__ int dpp_i(int x) {
    return __builtin_amdgcn_update_dpp(0, x, CTRL, 0xF, 0xF, true);
}

// Monotone u32 key of f32; low 8 bits = column idx (1..128). Exact ties (and
// sub-2^-15 near-ties) break to lowest idx. Exact f32 minv is re-read from the
// winning lane, so duals stay accurate; sub-quantum mis-picks only swap
// near-optimal alternates (loss impact ~1e-4 << 4.19e-2 threshold).
__device__ __forceinline__ unsigned f2key(float x, int idx) {
    unsigned b = __float_as_uint(x);
    unsigned m = (unsigned)(((int)b) >> 31) | 0x80000000u;
    return ((b ^ m) & ~0xFFu) | (unsigned)idx;
}
// ARR key: bit 8 = assigned-flag (prefer unassigned among ties).
__device__ __forceinline__ unsigned f2key_arr(float x, bool assigned, int idx) {
    unsigned b = __float_as_uint(x);
    unsigned m = (unsigned)(((int)b) >> 31) | 0x80000000u;
    return ((b ^ m) & ~0x1FFu) | (assigned ? 0x100u : 0u) | (unsigned)idx;
}

// 64-lane min over 32-bit packed keys, broadcast to all lanes.
__device__ __forceinline__ unsigned wave_minkey32(unsigned k) {
    { unsigned o = (unsigned)dpp_i<0xB1>((int)k);  k = umin2(k, o); }  // quad xor1
    { unsigned o = (unsigned)dpp_i<0x4E>((int)k);  k = umin2(k, o); }  // quad xor2
    { unsigned o = (unsigned)dpp_i<0x141>((int)k); k = umin2(k, o); }  // half_mirror (^4)
    { unsigned o = (unsigned)dpp_i<0x140>((int)k); k = umin2(k, o); }  // row_mirror (^8)
#if __has_builtin(__builtin_amdgcn_permlane16_swap)
    { uint2v r = __builtin_amdgcn_permlane16_swap(k, k, false, false);
      k = umin2(k, umin2(r.x, r.y)); }
#else
    { k = umin2(k, (unsigned)__shfl_xor((int)k, 16)); }
#endif
#if __has_builtin(__builtin_amdgcn_permlane32_swap)
    { uint2v r = __builtin_amdgcn_permlane32_swap(k, k, false, false);
      k = umin2(k, umin2(r.x, r.y)); }
#else
    { k = umin2(k, (unsigned)__shfl_xor((int)k, 32)); }
#endif
    return k;
}

// two-smallest merge; requires k1<=k2 and o1<=o2 (self-pair merge harmless).
__device__ __forceinline__ void min2m(unsigned& k1, unsigned& k2, unsigned o1, unsigned o2) {
    if (k1 <= o1) {
        k2 = umin2(k2, o1);
    } else {
        k2 = umin2(o2, k1);
        k1 = o1;
    }
}
// 64-lane (min, 2nd-min) over per-lane sorted pairs; broadcast.
__device__ __forceinline__ void wave_min2_32(unsigned& k1, unsigned& k2) {
    { unsigned o1 = (unsigned)dpp_i<0xB1>((int)k1),  o2 = (unsigned)dpp_i<0xB1>((int)k2);  min2m(k1, k2, o1, o2); }
    { unsigned o1 = (unsigned)dpp_i<0x4E>((int)k1),  o2 = (unsigned)dpp_i<0x4E>((int)k2);  min2m(k1, k2, o1, o2); }
    { unsigned o1 = (unsigned)dpp_i<0x141>((int)k1), o2 = (unsigned)dpp_i<0x141>((int)k2); min2m(k1, k2, o1, o2); }
    { unsigned o1 = (unsigned)dpp_i<0x140>((int)k1), o2 = (unsigned)dpp_i<0x140>((int)k2); min2m(k1, k2, o1, o2); }
#if __has_builtin(__builtin_amdgcn_permlane16_swap)
    { uint2v r1 = __builtin_amdgcn_permlane16_swap(k1, k1, false, false);
      uint2v r2 = __builtin_amdgcn_permlane16_swap(k2, k2, false, false);
      min2m(k1, k2, r1.x, r2.x); min2m(k1, k2, r1.y, r2.y); }
#else
    { unsigned o1 = (unsigned)__shfl_xor((int)k1, 16), o2 = (unsigned)__shfl_xor((int)k2, 16); min2m(k1, k2, o1, o2); }
#endif
#if __has_builtin(__builtin_amdgcn_permlane32_swap)
    { uint2v r1 = __builtin_amdgcn_permlane32_swap(k1, k1, false, false);
      uint2v r2 = __builtin_amdgcn_permlane32_swap(k2, k2, false, false);
      min2m(k1, k2, r1.x, r2.x); min2m(k1, k2, r1.y, r2.y); }
#else
    { unsigned o1 = (unsigned)__shfl_xor((int)k1, 32), o2 = (unsigned)__shfl_xor((int)k2, 32); min2m(k1, k2, o1, o2); }
#endif
}

__device__ __forceinline__ int rl_i(int v, int sl) {
    return __builtin_amdgcn_readlane(v, sl);
}
__device__ __forceinline__ float rl_f(float v, int sl) {
    return __int_as_float(__builtin_amdgcn_readlane(__float_as_int(v), sl));
}

// ---- Hungarian: LDS cost planes + colred + ARR(tie-skip) + shift-SAP ------

__global__ __launch_bounds__(64, 1) void hungarian_kernel(
    const float* __restrict__ pv,     // [B,V,3]
    const float* __restrict__ pe,     // [B,V]
    const float* __restrict__ tv,     // [B,V,3]
    const int*   __restrict__ counts, // [B]
    double* __restrict__ ws_sl1)      // [B]
{
    const int b = blockIdx.x;
    const int lane = threadIdx.x;
    const int c = counts[b];

    __shared__ float  s_costA[NV * 64];  // [row][lane] = C[row][lane+1]   (32 KB)
    __shared__ float  s_costB[NV * 64];  // [row][lane] = C[row][lane+65]  (32 KB)
    __shared__ float4 s_row[NV];
    __shared__ float  s_pe[NV];
    __shared__ int    s_colpick[NV];
    __shared__ int    s_rowacc[NV];

    const float* pvb = pv + (size_t)b * NV * 3;
    const float* peb = pe + (size_t)b * NV;
    const float* tvb = tv + (size_t)b * NV * 3;

    // lane owns rows/cols (1-based): rA=jA=lane+1, rB=jB=lane+65
    {
        float x0 = pvb[lane * 3 + 0], y0 = pvb[lane * 3 + 1], z0 = pvb[lane * 3 + 2];
        float x1 = pvb[(lane + 64) * 3 + 0], y1 = pvb[(lane + 64) * 3 + 1], z1 = pvb[(lane + 64) * 3 + 2];
        float e0 = peb[lane], e1 = peb[lane + 64];
        s_row[lane]      = make_float4(x0, y0, z0, fabsf(e0 - 1.0f));
        s_row[lane + 64] = make_float4(x1, y1, z1, fabsf(e1 - 1.0f));
        s_pe[lane]       = e0;
        s_pe[lane + 64]  = e1;
    }
    const float tAx = tvb[lane * 3 + 0], tAy = tvb[lane * 3 + 1], tAz = tvb[lane * 3 + 2];
    const float tBx = tvb[(lane + 64) * 3 + 0], tBy = tvb[(lane + 64) * 3 + 1], tBz = tvb[(lane + 64) * 3 + 2];

    const int jA = lane + 1, jB = lane + 65;
    const int rA = lane + 1, rB = lane + 65;
    const bool realA = (jA <= c), realB = (jB <= c);

    __syncthreads();

    // ---- Phase 0: build cost planes (f32-exact, reference op order) -------
    #pragma unroll 4
    for (int r = 0; r < NV; ++r) {
        float4 row = s_row[r];
        float per = s_pe[r];
        float cAv = realA ? (((fabsf(row.x - tAx) + fabsf(row.y - tAy)) + fabsf(row.z - tAz)) + row.w) : per;
        float cBv = realB ? (((fabsf(row.x - tBx) + fabsf(row.y - tBy)) + fabsf(row.z - tBz)) + row.w) : per;
        s_costA[r * 64 + lane] = cAv;
        s_costB[r * 64 + lane] = cBv;
    }
    __syncthreads();

    // ---- Phase A: column reduction + greedy tight assignment --------------
    float bestA = 3.4e38f, bestB = 3.4e38f;
    int bestAr = 1, bestBr = 1;
    #pragma unroll 4
    for (int r = 0; r < NV; ++r) {
        float ca = s_costA[r * 64 + lane];
        float cb = s_costB[r * 64 + lane];
        if (ca < bestA) { bestA = ca; bestAr = r + 1; }
        if (cb < bestB) { bestB = cb; bestBr = r + 1; }
    }
    float vA = bestA, vB = bestB;   // column potentials
    float uA = 0.0f, uB = 0.0f;     // row potentials

    s_colpick[jA - 1] = bestAr;
    s_colpick[jB - 1] = bestBr;
    __syncthreads();
    int xA = 0, xB = 0;             // x[row] = col (0 free)
    #pragma unroll 4
    for (int j = 0; j < NV; ++j) {
        int pick = s_colpick[j];
        if (xA == 0 && pick == rA) xA = j + 1;
        if (xB == 0 && pick == rB) xB = j + 1;
    }
    s_rowacc[rA - 1] = xA;
    s_rowacc[rB - 1] = xB;
    __syncthreads();
    int pA = (s_rowacc[bestAr - 1] == jA) ? bestAr : 0;  // y[col] = row (0 free)
    int pB = (s_rowacc[bestBr - 1] == jB) ? bestBr : 0;

    u64 mA = __ballot(xA == 0);   // bit l: row l+1 unassigned
    u64 mB = __ballot(xB == 0);   // bit l: row l+65 unassigned
    u64 dA = 0ull, dB = 0ull;     // deferred (tie-skipped) rows -> Phase C

    // ---- Phase B: augmenting row reduction (tie-skip, clamped duals) ------
    int steps = 0;
    while ((mA | mB) != 0ull && steps < 600) {
        ++steps;
        const int i0 = mA ? (__builtin_ctzll(mA) + 1) : (__builtin_ctzll(mB) + 65);
        const bool hi = (i0 > 64);
        const int sl = (i0 - 1) & 63;

        const float rjA = s_costA[(i0 - 1) * 64 + lane] - vA;
        const float rjB = s_costB[(i0 - 1) * 64 + lane] - vB;

        unsigned k1 = f2key_arr(rjA, pA != 0, jA);
        unsigned k2 = f2key_arr(rjB, pB != 0, jB);
        if (k2 < k1) { unsigned t = k1; k1 = k2; k2 = t; }
        wave_min2_32(k1, k2);

        const int j1 = (int)(__builtin_amdgcn_readfirstlane(k1) & 0xFFu);
        const int j2 = (int)(__builtin_amdgcn_readfirstlane(k2) & 0xFFu);
        const bool h1 = (j1 > 64); const int s1 = (j1 - 1) & 63;
        const bool h2 = (j2 > 64); const int s2 = (j2 - 1) & 63;
        const float m1 = rl_f(h1 ? rjB : rjA, s1);
        const float m2 = rl_f(h2 ? rjB : rjA, s2);
        const int kdisp = rl_i(h1 ? pB : pA, s1);   // row currently on j1

        if (hi) mB &= ~(1ull << sl); else mA &= ~(1ull << sl);

        if (kdisp != 0 && !(m2 > m1)) {
            // tied displacement: no dual progress possible; defer to Phase C
            if (hi) dB |= (1ull << sl); else dA |= (1ull << sl);
            continue;
        }
        const float dlt = fmaxf(m2 - m1, 0.0f);
        if (jA == j1) { vA -= dlt; pA = i0; }
        if (jB == j1) { vB -= dlt; pB = i0; }
        if (rA == i0) { uA = m2; xA = j1; }
        if (rB == i0) { uB = m2; xB = j1; }
        if (kdisp != 0) {
            if (rA == kdisp) xA = 0;
            if (rB == kdisp) xB = 0;
            if (kdisp > 64) mB |= (1ull << (kdisp - 65)); else mA |= (1ull << (kdisp - 1));
        }
    }
    mA |= dA;
    mB |= dB;

    // ---- Phase C: shortest augmenting paths, shift-trick (no per-iter dual
    //      updates). minvRaw[j] = min over settled rows of (C-u0-v)+S_settle;
    //      winning minvRaw IS the next shift S. At path end:
    //      v[used] -= S_final - S_use ; u[settled] += S_final - S_settle.
    const float INF = 3.4e38f;
    while ((mA | mB) != 0ull) {
        const int f = mA ? (__builtin_ctzll(mA) + 1) : (__builtin_ctzll(mB) + 65);
        if (f <= 64) mA &= ~(1ull << (f - 1)); else mB &= ~(1ull << (f - 65));

        float minvA = INF, minvB = INF;
        int wayA = 0, wayB = 0;
        bool cuA = false, cuB = false;    // my column used
        float SuseA = 0.0f, SuseB = 0.0f;
        bool rsA = (rA == f), rsB = (rB == f);  // my rows settled
        float SsetA = 0.0f, SsetB = 0.0f;
        int j0 = 0;
        int i0 = f;
        float S = 0.0f;

        float u0 = rl_f((f > 64) ? uB : uA, (f - 1) & 63);
        float pre = u0;                   // u0 - S with S=0
        float cA = s_costA[(f - 1) * 64 + lane];
        float cB = s_costB[(f - 1) * 64 + lane];

        for (;;) {
            if (!cuA) { float cur = (cA - pre) - vA; if (cur < minvA) { minvA = cur; wayA = j0; } }
            if (!cuB) { float cur = (cB - pre) - vB; if (cur < minvB) { minvB = cur; wayB = j0; } }

            unsigned k = umin2(f2key(minvA, jA), f2key(minvB, jB));
            k = wave_minkey32(k);

            const int idx = (int)(__builtin_amdgcn_readfirstlane(k) & 0xFFu);
            const bool hij = (idx > 64);
            const int slj = (idx - 1) & 63;
            const float Snew = rl_f(hij ? minvB : minvA, slj);  // exact minvRaw
            i0 = rl_i(hij ? pB : pA, slj);
            j0 = idx;

            if (jA == j0) { cuA = true; SuseA = Snew; minvA = INF; }
            if (jB == j0) { cuB = true; SuseB = Snew; minvB = INF; }
            S = Snew;
            if (i0 == 0) break;

            if (rA == i0) { rsA = true; SsetA = Snew; }
            if (rB == i0) { rsB = true; SsetB = Snew; }
            u0 = rl_f((i0 > 64) ? uB : uA, (i0 - 1) & 63);
            pre = u0 - S;
            cA = s_costA[(i0 - 1) * 64 + lane];
            cB = s_costB[(i0 - 1) * 64 + lane];
        }

        if (cuA) vA -= (S - SuseA);
        if (cuB) vB -= (S - SuseB);
        if (rsA) uA += (S - SsetA);
        if (rsB) uB += (S - SsetB);

        // augment along way[] chain
        int j = j0;
        while (j != 0) {
            int j1 = rl_i((j <= 64) ? wayA : wayB, (j - 1) & 63);
            int pnew = (j1 == 0) ? f : rl_i((j1 <= 64) ? pA : pB, (j1 - 1) & 63);
            if (jA == j) pA = pnew;
            if (jB == j) pB = pnew;
            j = j1;
        }
    }

    // ---- SmoothL1 over matched pairs (cols < c) ---------------------------
    double acc = 0.0;
    if (lane < c) {
        float4 prow = s_row[pA - 1];
        acc += (double)(sl1f(prow.x - tAx) + sl1f(prow.y - tAy) + sl1f(prow.z - tAz));
    }
    if (lane + 64 < c) {
        float4 prow = s_row[pB - 1];
        acc += (double)(sl1f(prow.x - tBx) + sl1f(prow.y - tBy) + sl1f(prow.z - tBz));
    }
    for (int off = 1; off < 64; off <<= 1) acc += __shfl_xor(acc, off);
    if (lane == 0) ws_sl1[b] = acc;
}

// ---- BCE / finalize -------------------------------------------------------

__device__ __forceinline__ double bce_term(float p, float t) {
    float logp = fmaxf(logf(p), -100.0f);
    float logq = fmaxf(logf(1.0f - p), -100.0f);
    return (double)(-(t * logp + (1.0f - t) * logq));
}

__global__ __launch_bounds__(256) void bce_exist_kernel(
    const float* __restrict__ pe, const int* __restrict__ te, double* __restrict__ out)
{
    const int tid = threadIdx.x;
    double acc = 0.0;
    for (int i = tid; i < N_EX; i += 256)
        acc += bce_term(pe[i], (float)te[i]);
    for (int off = 1; off < 64; off <<= 1) acc += __shfl_xor(acc, off);
    __shared__ double s[4];
    if ((tid & 63) == 0) s[tid >> 6] = acc;
    __syncthreads();
    if (tid == 0) out[0] = s[0] + s[1] + s[2] + s[3];
}

__global__ __launch_bounds__(256) void bce_edge_kernel(
    const float* __restrict__ p, const float* __restrict__ t, double* __restrict__ out)
{
    const int tid = threadIdx.x;
    double acc = 0.0;
    for (int i = blockIdx.x * 256 + tid; i < N_EDGE; i += 256 * 256)
        acc += bce_term(p[i], t[i]);
    for (int off = 1; off < 64; off <<= 1) acc += __shfl_xor(acc, off);
    __shared__ double s[4];
    if ((tid & 63) == 0) s[tid >> 6] = acc;
    __syncthreads();
    if (tid == 0) out[blockIdx.x] = s[0] + s[1] + s[2] + s[3];
}

__global__ __launch_bounds__(64) void finalize_kernel(
    const double* __restrict__ ws, const int* __restrict__ counts, float* __restrict__ out)
{
    const int lane = threadIdx.x;
    double vsum = ws[lane];
    double csum = (double)counts[lane];
    double edsum = 0.0;
    for (int k = lane; k < 256; k += 64) edsum += ws[128 + k];
    for (int off = 1; off < 64; off <<= 1) {
        vsum  += __shfl_xor(vsum, off);
        csum  += __shfl_xor(csum, off);
        edsum += __shfl_xor(edsum, off);
    }
    if (lane == 0) {
        double vloss  = vsum / (3.0 * csum);
        double eloss  = ws[64] / (double)N_EX;
        double edloss = edsum / (double)N_EDGE;
        double total  = vloss + eloss + edloss;
        out[0] = (float)total;
        out[1] = (float)vloss;
        out[2] = (float)eloss;
        out[3] = (float)edloss;
    }
}

extern "C" void kernel_launch(void* const* d_in, const int* in_sizes, int n_in,
                              void* d_out, int out_size, void* d_ws, size_t ws_size,
                              hipStream_t stream) {
    const float* pv     = (const float*)d_in[0];
    const float* pe     = (const float*)d_in[1];
    const float* pedge  = (const float*)d_in[2];
    const float* tv     = (const float*)d_in[3];
    const int*   te     = (const int*)d_in[4];
    const float* elab   = (const float*)d_in[5];
    const int*   counts = (const int*)d_in[6];
    double* ws = (double*)d_ws;
    float* out = (float*)d_out;

    hipLaunchKernelGGL(hungarian_kernel, dim3(NB), dim3(64), 0, stream, pv, pe, tv, counts, ws);
    hipLaunchKernelGGL(bce_exist_kernel, dim3(1), dim3(256), 0, stream, pe, te, ws + 64);
    hipLaunchKernelGGL(bce_edge_kernel, dim3(256), dim3(256), 0, stream, pedge, elab, ws + 128);
    hipLaunchKernelGGL(finalize_kernel, dim3(1), dim3(64), 0, stream, ws, counts, out);
}

// Round 7
// 879.239 us; speedup vs baseline: 7.7188x; 1.4792x over previous
//
#include <hip/hip_runtime.h>
#include <math.h>

#define NB 64
#define NV 128
#define NEDGE_PER 8128
#define N_EDGE (NB * NEDGE_PER)   // 520192
#define N_EX (NB * NV)            // 8192
#define BID_ROUNDS 16
#define ARR_CAP 256

// workspace layout (doubles):
// ws[0..63]    per-sample SmoothL1 sums
// ws[64]       existence BCE sum
// ws[128..383] edge BCE partials (256 blocks)

typedef unsigned long long u64;
typedef unsigned int uint2v __attribute__((ext_vector_type(2)));

__device__ __forceinline__ float sl1f(float d) {
    d = fabsf(d);
    return d < 1.0f ? 0.5f * d * d : d - 0.5f;
}
__device__ __forceinline__ unsigned umin2(unsigned a, unsigned b) { return a < b ? a : b; }

// ---- cross-lane helpers ---------------------------------------------------

template <int CTRL>
__device__ __forceinline__ int dpp_i(int x) {
    return __builtin_amdgcn_update_dpp(0, x, CTRL, 0xF, 0xF, true);
}

// Monotone u32 key of f32; low 8 bits = column idx (1..128). Exact ties break
// to lowest idx; exact f32 minv is re-read from the winning lane so duals stay
// accurate. Sub-quantum mis-picks only swap near-optimal alternates.
__device__ __forceinline__ unsigned f2key(float x, int idx) {
    unsigned b = __float_as_uint(x);
    unsigned m = (unsigned)(((int)b) >> 31) | 0x80000000u;
    return ((b ^ m) & ~0xFFu) | (unsigned)idx;
}
// ARR key: bit 8 = assigned-flag (prefer unassigned among ties).
__device__ __forceinline__ unsigned f2key_arr(float x, bool assigned, int idx) {
    unsigned b = __float_as_uint(x);
    unsigned m = (unsigned)(((int)b) >> 31) | 0x80000000u;
    return ((b ^ m) & ~0x1FFu) | (assigned ? 0x100u : 0u) | (unsigned)idx;
}
// bid key: monotone map of bid >= 0, low 8 bits = row idx; max-reduce. >0 always.
__device__ __forceinline__ unsigned bidkey(float b, int row) {
    return ((__float_as_uint(b) | 0x80000000u) & ~0xFFu) | (unsigned)row;
}

// 64-lane min over 32-bit packed keys, broadcast to all lanes.
__device__ __forceinline__ unsigned wave_minkey32(unsigned k) {
    { unsigned o = (unsigned)dpp_i<0xB1>((int)k);  k = umin2(k, o); }
    { unsigned o = (unsigned)dpp_i<0x4E>((int)k);  k = umin2(k, o); }
    { unsigned o = (unsigned)dpp_i<0x141>((int)k); k = umin2(k, o); }
    { unsigned o = (unsigned)dpp_i<0x140>((int)k); k = umin2(k, o); }
#if __has_builtin(__builtin_amdgcn_permlane16_swap)
    { uint2v r = __builtin_amdgcn_permlane16_swap(k, k, false, false);
      k = umin2(k, umin2(r.x, r.y)); }
#else
    { k = umin2(k, (unsigned)__shfl_xor((int)k, 16)); }
#endif
#if __has_builtin(__builtin_amdgcn_permlane32_swap)
    { uint2v r = __builtin_amdgcn_permlane32_swap(k, k, false, false);
      k = umin2(k, umin2(r.x, r.y)); }
#else
    { k = umin2(k, (unsigned)__shfl_xor((int)k, 32)); }
#endif
    return k;
}

// two-smallest merge; requires k1<=k2 and o1<=o2 (self-pair merge harmless).
__device__ __forceinline__ void min2m(unsigned& k1, unsigned& k2, unsigned o1, unsigned o2) {
    if (k1 <= o1) {
        k2 = umin2(k2, o1);
    } else {
        k2 = umin2(o2, k1);
        k1 = o1;
    }
}
// 64-lane (min, 2nd-min) over per-lane sorted pairs; broadcast.
__device__ __forceinline__ void wave_min2_32(unsigned& k1, unsigned& k2) {
    { unsigned o1 = (unsigned)dpp_i<0xB1>((int)k1),  o2 = (unsigned)dpp_i<0xB1>((int)k2);  min2m(k1, k2, o1, o2); }
    { unsigned o1 = (unsigned)dpp_i<0x4E>((int)k1),  o2 = (unsigned)dpp_i<0x4E>((int)k2);  min2m(k1, k2, o1, o2); }
    { unsigned o1 = (unsigned)dpp_i<0x141>((int)k1), o2 = (unsigned)dpp_i<0x141>((int)k2); min2m(k1, k2, o1, o2); }
    { unsigned o1 = (unsigned)dpp_i<0x140>((int)k1), o2 = (unsigned)dpp_i<0x140>((int)k2); min2m(k1, k2, o1, o2); }
#if __has_builtin(__builtin_amdgcn_permlane16_swap)
    { uint2v r1 = __builtin_amdgcn_permlane16_swap(k1, k1, false, false);
      uint2v r2 = __builtin_amdgcn_permlane16_swap(k2, k2, false, false);
      min2m(k1, k2, r1.x, r2.x); min2m(k1, k2, r1.y, r2.y); }
#else
    { unsigned o1 = (unsigned)__shfl_xor((int)k1, 16), o2 = (unsigned)__shfl_xor((int)k2, 16); min2m(k1, k2, o1, o2); }
#endif
#if __has_builtin(__builtin_amdgcn_permlane32_swap)
    { uint2v r1 = __builtin_amdgcn_permlane32_swap(k1, k1, false, false);
      uint2v r2 = __builtin_amdgcn_permlane32_swap(k2, k2, false, false);
      min2m(k1, k2, r1.x, r2.x); min2m(k1, k2, r1.y, r2.y); }
#else
    { unsigned o1 = (unsigned)__shfl_xor((int)k1, 32), o2 = (unsigned)__shfl_xor((int)k2, 32); min2m(k1, k2, o1, o2); }
#endif
}

__device__ __forceinline__ int rl_i(int v, int sl) {
    return __builtin_amdgcn_readlane(v, sl);
}
__device__ __forceinline__ float rl_f(float v, int sl) {
    return __int_as_float(__builtin_amdgcn_readlane(__float_as_int(v), sl));
}

// ---- Hungarian: swizzled cost planes + colred + Jacobi auction rounds
//      + serial ARR + shift-trick SAP. One wave per sample. ------------------

// cost plane layout: entry (0-based row r, 0-based col-half c0) stored at
// r*64 + (c0 ^ (r&31)). Row-broadcast reads (uniform r): per-lane addr
// lane^const -> 2-way banks (free). Per-lane row scans (r=own row): addr
// (j0^(r&31)) -> 2-way banks (free).

__global__ __launch_bounds__(64, 1) void hungarian_kernel(
    const float* __restrict__ pv,     // [B,V,3]
    const float* __restrict__ pe,     // [B,V]
    const float* __restrict__ tv,     // [B,V,3]
    const int*   __restrict__ counts, // [B]
    double* __restrict__ ws_sl1)      // [B]
{
    const int b = blockIdx.x;
    const int lane = threadIdx.x;
    const int c = counts[b];

    __shared__ float  s_costA[NV * 64];  // cols 1..64   (32 KB, swizzled)
    __shared__ float  s_costB[NV * 64];  // cols 65..128 (32 KB, swizzled)
    __shared__ float4 s_row[NV];
    __shared__ float  s_pe[NV];
    __shared__ float  s_v[NV];           // column potentials (LDS master copy)
    __shared__ float  s_u[NV];           // row potentials
    __shared__ int    s_x[NV];           // row -> col (0 = free)
    __shared__ float  s_rm1[NV], s_rm2[NV];
    __shared__ unsigned s_bid[NV];

    const float* pvb = pv + (size_t)b * NV * 3;
    const float* peb = pe + (size_t)b * NV;
    const float* tvb = tv + (size_t)b * NV * 3;

    // lane owns rows/cols (1-based): rA=jA=lane+1, rB=jB=lane+65
    {
        float x0 = pvb[lane * 3 + 0], y0 = pvb[lane * 3 + 1], z0 = pvb[lane * 3 + 2];
        float x1 = pvb[(lane + 64) * 3 + 0], y1 = pvb[(lane + 64) * 3 + 1], z1 = pvb[(lane + 64) * 3 + 2];
        float e0 = peb[lane], e1 = peb[lane + 64];
        s_row[lane]      = make_float4(x0, y0, z0, fabsf(e0 - 1.0f));
        s_row[lane + 64] = make_float4(x1, y1, z1, fabsf(e1 - 1.0f));
        s_pe[lane]       = e0;
        s_pe[lane + 64]  = e1;
    }
    const float tAx = tvb[lane * 3 + 0], tAy = tvb[lane * 3 + 1], tAz = tvb[lane * 3 + 2];
    const float tBx = tvb[(lane + 64) * 3 + 0], tBy = tvb[(lane + 64) * 3 + 1], tBz = tvb[(lane + 64) * 3 + 2];

    const int jA = lane + 1, jB = lane + 65;
    const int rA = lane + 1, rB = lane + 65;
    const bool realA = (jA <= c), realB = (jB <= c);

    __syncthreads();

    // ---- Phase 0: build swizzled cost planes (f32-exact, reference order) --
    #pragma unroll 4
    for (int r = 0; r < NV; ++r) {
        float4 row = s_row[r];
        float per = s_pe[r];
        float cAv = realA ? (((fabsf(row.x - tAx) + fabsf(row.y - tAy)) + fabsf(row.z - tAz)) + row.w) : per;
        float cBv = realB ? (((fabsf(row.x - tBx) + fabsf(row.y - tBy)) + fabsf(row.z - tBz)) + row.w) : per;
        const int a = r * 64 + (lane ^ (r & 31));
        s_costA[a] = cAv;
        s_costB[a] = cBv;
    }
    __syncthreads();

    // ---- Phase A: column reduction (v[j] = min_i C[i][j]) -----------------
    float bestA = 3.4e38f, bestB = 3.4e38f;
    #pragma unroll 4
    for (int r = 0; r < NV; ++r) {
        const int a = r * 64 + (lane ^ (r & 31));
        float ca = s_costA[a];
        float cb = s_costB[a];
        bestA = fminf(bestA, ca);
        bestB = fminf(bestB, cb);
    }
    float vA = bestA, vB = bestB;   // this lane's column potentials
    float uA = 0.0f, uB = 0.0f;
    int pA = 0, pB = 0;             // col -> row (0 = free)
    s_v[jA - 1] = vA; s_v[jB - 1] = vB;
    s_x[rA - 1] = 0;  s_x[rB - 1] = 0;
    s_u[rA - 1] = 0.0f; s_u[rB - 1] = 0.0f;

    // ---- Phase B': Jacobi auction rounds (parallel row bids) --------------
    // Safe: v only decreases => u+v <= C stays feasible; winner set exactly
    // tight (u[w]=m2, v[j1]-=(m2-m1)). Rotation tie-break spreads exact ties
    // (dummy cols) across rows.
    for (int round = 0; round < BID_ROUNDS; ++round) {
        const int xAcur = s_x[rA - 1];
        const int xBcur = s_x[rB - 1];
        const u64 fA = __ballot(xAcur == 0);
        const u64 fB = __ballot(xBcur == 0);
        if ((fA | fB) == 0ull) break;

        s_bid[jA - 1] = 0u;
        s_bid[jB - 1] = 0u;

        // scan my free rows (exact f32 min/second-min, rotated tie-break)
        #pragma unroll
        for (int half = 0; half < 2; ++half) {
            const int ri = (half == 0) ? rA : rB;            // 1-based row
            const int xcur = (half == 0) ? xAcur : xBcur;
            if (xcur != 0) continue;
            const int r0 = ri - 1;
            const int swz = r0 & 31;
            float m1 = 3.4e38f, m2 = 3.4e38f;
            int j1 = 0, rot1 = 1000;
            #pragma unroll 4
            for (int j0 = 0; j0 < 64; ++j0) {
                const int a = r0 * 64 + (j0 ^ swz);
                float ca = s_costA[a] - s_v[j0];
                float cb = s_costB[a] - s_v[j0 + 64];
                int rotA = (j0 + 1 - ri) & 127;
                int rotB = (j0 + 65 - ri) & 127;
                if (ca < m1 || (ca == m1 && rotA < rot1)) { m2 = m1; m1 = ca; j1 = j0 + 1; rot1 = rotA; }
                else if (ca < m2) m2 = ca;
                if (cb < m1 || (cb == m1 && rotB < rot1)) { m2 = m1; m1 = cb; j1 = j0 + 65; rot1 = rotB; }
                else if (cb < m2) m2 = cb;
            }
            s_rm1[r0] = m1;
            s_rm2[r0] = m2;
            atomicMax(&s_bid[j1 - 1], bidkey(m2 - m1, ri));
        }

        // column accept (this lane's two columns)
        {
            unsigned bk = s_bid[jA - 1];
            if (bk != 0u) {
                const int w = (int)(bk & 0xFFu);
                float m1w = s_rm1[w - 1], m2w = s_rm2[w - 1];
                vA -= (m2w - m1w);
                s_v[jA - 1] = vA;
                int old = pA; pA = w;
                s_x[w - 1] = jA;
                s_u[w - 1] = m2w;
                if (old) s_x[old - 1] = 0;
            }
        }
        {
            unsigned bk = s_bid[jB - 1];
            if (bk != 0u) {
                const int w = (int)(bk & 0xFFu);
                float m1w = s_rm1[w - 1], m2w = s_rm2[w - 1];
                vB -= (m2w - m1w);
                s_v[jB - 1] = vB;
                int old = pB; pB = w;
                s_x[w - 1] = jB;
                s_u[w - 1] = m2w;
                if (old) s_x[old - 1] = 0;
            }
        }
    }

    // load post-round row state into registers
    uA = s_u[rA - 1]; uB = s_u[rB - 1];
    u64 mA = __ballot(s_x[rA - 1] == 0);
    u64 mB = __ballot(s_x[rB - 1] == 0);
    u64 dA = 0ull, dB = 0ull;

    // ---- Phase B: serial ARR for leftovers (tie-skip, clamped duals) ------
    int steps = 0;
    while ((mA | mB) != 0ull && steps < ARR_CAP) {
        ++steps;
        const int i0 = mA ? (__builtin_ctzll(mA) + 1) : (__builtin_ctzll(mB) + 65);
        const bool hi = (i0 > 64);
        const int sl = (i0 - 1) & 63;
        const int ri0 = i0 - 1;
        const int a = ri0 * 64 + (lane ^ (ri0 & 31));

        const float rjA = s_costA[a] - vA;
        const float rjB = s_costB[a] - vB;

        unsigned k1 = f2key_arr(rjA, pA != 0, jA);
        unsigned k2 = f2key_arr(rjB, pB != 0, jB);
        if (k2 < k1) { unsigned t = k1; k1 = k2; k2 = t; }
        wave_min2_32(k1, k2);

        const int j1 = (int)(__builtin_amdgcn_readfirstlane(k1) & 0xFFu);
        const int j2 = (int)(__builtin_amdgcn_readfirstlane(k2) & 0xFFu);
        const bool h1 = (j1 > 64); const int s1 = (j1 - 1) & 63;
        const bool h2 = (j2 > 64); const int s2 = (j2 - 1) & 63;
        const float m1 = h1 ? rl_f(rjB, s1) : rl_f(rjA, s1);
        const float m2 = h2 ? rl_f(rjB, s2) : rl_f(rjA, s2);
        const int kdisp = h1 ? rl_i(pB, s1) : rl_i(pA, s1);

        if (hi) mB &= ~(1ull << sl); else mA &= ~(1ull << sl);

        if (kdisp != 0 && !(m2 > m1)) {
            if (hi) dB |= (1ull << sl); else dA |= (1ull << sl);
            continue;
        }
        const float dlt = fmaxf(m2 - m1, 0.0f);
        if (jA == j1) { vA -= dlt; pA = i0; }
        if (jB == j1) { vB -= dlt; pB = i0; }
        if (rA == i0) { uA = m2; }
        if (rB == i0) { uB = m2; }
        if (kdisp != 0) {
            if (kdisp > 64) mB |= (1ull << (kdisp - 65)); else mA |= (1ull << (kdisp - 1));
        }
    }
    mA |= dA;
    mB |= dB;

    // ---- Phase C: shortest augmenting paths, shift-trick ------------------
    const float INF = 3.4e38f;
    while ((mA | mB) != 0ull) {
        const int f = mA ? (__builtin_ctzll(mA) + 1) : (__builtin_ctzll(mB) + 65);
        if (f <= 64) mA &= ~(1ull << (f - 1)); else mB &= ~(1ull << (f - 65));

        float minvA = INF, minvB = INF;
        int wayA = 0, wayB = 0;
        bool cuA = false, cuB = false;
        float SuseA = 0.0f, SuseB = 0.0f;
        bool rsA = (rA == f), rsB = (rB == f);
        float SsetA = 0.0f, SsetB = 0.0f;
        int j0 = 0;
        int i0 = f;
        float S = 0.0f;

        float u0 = (f > 64) ? rl_f(uB, (f - 1) & 63) : rl_f(uA, (f - 1) & 63);
        float pre = u0;
        int ri0 = f - 1;
        int a = ri0 * 64 + (lane ^ (ri0 & 31));
        float cA = s_costA[a];
        float cB = s_costB[a];

        for (;;) {
            if (!cuA) { float cur = (cA - pre) - vA; if (cur < minvA) { minvA = cur; wayA = j0; } }
            if (!cuB) { float cur = (cB - pre) - vB; if (cur < minvB) { minvB = cur; wayB = j0; } }

            unsigned k = umin2(f2key(minvA, jA), f2key(minvB, jB));
            k = wave_minkey32(k);

            const int idx = (int)(__builtin_amdgcn_readfirstlane(k) & 0xFFu);
            const bool hij = (idx > 64);
            const int slj = (idx - 1) & 63;
            const float SnA = rl_f(minvA, slj);
            const float SnB = rl_f(minvB, slj);
            const float Snew = hij ? SnB : SnA;
            const int iA = rl_i(pA, slj);
            const int iB = rl_i(pB, slj);
            i0 = hij ? iB : iA;
            j0 = idx;

            if (jA == j0) { cuA = true; SuseA = Snew; minvA = INF; }
            if (jB == j0) { cuB = true; SuseB = Snew; minvB = INF; }
            S = Snew;
            if (i0 == 0) break;

            if (rA == i0) { rsA = true; SsetA = Snew; }
            if (rB == i0) { rsB = true; SsetB = Snew; }
            u0 = (i0 > 64) ? rl_f(uB, (i0 - 1) & 63) : rl_f(uA, (i0 - 1) & 63);
            pre = u0 - S;
            ri0 = i0 - 1;
            a = ri0 * 64 + (lane ^ (ri0 & 31));
            cA = s_costA[a];
            cB = s_costB[a];
        }

        if (cuA) vA -= (S - SuseA);
        if (cuB) vB -= (S - SuseB);
        if (rsA) uA += (S - SsetA);
        if (rsB) uB += (S - SsetB);

        // augment along way[] chain
        int j = j0;
        while (j != 0) {
            int j1 = rl_i((j <= 64) ? wayA : wayB, (j - 1) & 63);
            int pnew = (j1 == 0) ? f : rl_i((j1 <= 64) ? pA : pB, (j1 - 1) & 63);
            if (jA == j) pA = pnew;
            if (jB == j) pB = pnew;
            j = j1;
        }
    }

    // ---- SmoothL1 over matched pairs (cols < c) ---------------------------
    double acc = 0.0;
    if (lane < c) {
        float4 prow = s_row[pA - 1];
        acc += (double)(sl1f(prow.x - tAx) + sl1f(prow.y - tAy) + sl1f(prow.z - tAz));
    }
    if (lane + 64 < c) {
        float4 prow = s_row[pB - 1];
        acc += (double)(sl1f(prow.x - tBx) + sl1f(prow.y - tBy) + sl1f(prow.z - tBz));
    }
    for (int off = 1; off < 64; off <<= 1) acc += __shfl_xor(acc, off);
    if (lane == 0) ws_sl1[b] = acc;
}

// ---- BCE / finalize -------------------------------------------------------

__device__ __forceinline__ double bce_term(float p, float t) {
    float logp = fmaxf(logf(p), -100.0f);
    float logq = fmaxf(logf(1.0f - p), -100.0f);
    return (double)(-(t * logp + (1.0f - t) * logq));
}

__global__ __launch_bounds__(256) void bce_exist_kernel(
    const float* __restrict__ pe, const int* __restrict__ te, double* __restrict__ out)
{
    const int tid = threadIdx.x;
    double acc = 0.0;
    for (int i = tid; i < N_EX; i += 256)
        acc += bce_term(pe[i], (float)te[i]);
    for (int off = 1; off < 64; off <<= 1) acc += __shfl_xor(acc, off);
    __shared__ double s[4];
    if ((tid & 63) == 0) s[tid >> 6] = acc;
    __syncthreads();
    if (tid == 0) out[0] = s[0] + s[1] + s[2] + s[3];
}

__global__ __launch_bounds__(256) void bce_edge_kernel(
    const float* __restrict__ p, const float* __restrict__ t, double* __restrict__ out)
{
    const int tid = threadIdx.x;
    double acc = 0.0;
    for (int i = blockIdx.x * 256 + tid; i < N_EDGE; i += 256 * 256)
        acc += bce_term(p[i], t[i]);
    for (int off = 1; off < 64; off <<= 1) acc += __shfl_xor(acc, off);
    __shared__ double s[4];
    if ((tid & 63) == 0) s[tid >> 6] = acc;
    __syncthreads();
    if (tid == 0) out[blockIdx.x] = s[0] + s[1] + s[2] + s[3];
}

__global__ __launch_bounds__(64) void finalize_kernel(
    const double* __restrict__ ws, const int* __restrict__ counts, float* __restrict__ out)
{
    const int lane = threadIdx.x;
    double vsum = ws[lane];
    double csum = (double)counts[lane];
    double edsum = 0.0;
    for (int k = lane; k < 256; k += 64) edsum += ws[128 + k];
    for (int off = 1; off < 64; off <<= 1) {
        vsum  += __shfl_xor(vsum, off);
        csum  += __shfl_xor(csum, off);
        edsum += __shfl_xor(edsum, off);
    }
    if (lane == 0) {
        double vloss  = vsum / (3.0 * csum);
        double eloss  = ws[64] / (double)N_EX;
        double edloss = edsum / (double)N_EDGE;
        double total  = vloss + eloss + edloss;
        out[0] = (float)total;
        out[1] = (float)vloss;
        out[2] = (float)eloss;
        out[3] = (float)edloss;
    }
}

extern "C" void kernel_launch(void* const* d_in, const int* in_sizes, int n_in,
                              void* d_out, int out_size, void* d_ws, size_t ws_size,
                              hipStream_t stream) {
    const float* pv     = (const float*)d_in[0];
    const float* pe     = (const float*)d_in[1];
    const float* pedge  = (const float*)d_in[2];
    const float* tv     = (const float*)d_in[3];
    const int*   te     = (const int*)d_in[4];
    const float* elab   = (const float*)d_in[5];
    const int*   counts = (const int*)d_in[6];
    double* ws = (double*)d_ws;
    float* out = (float*)d_out;

    hipLaunchKernelGGL(hungarian_kernel, dim3(NB), dim3(64), 0, stream, pv, pe, tv, counts, ws);
    hipLaunchKernelGGL(bce_exist_kernel, dim3(1), dim3(256), 0, stream, pe, te, ws + 64);
    hipLaunchKernelGGL(bce_edge_kernel, dim3(256), dim3(256), 0, stream, pedge, elab, ws + 128);
    hipLaunchKernelGGL(finalize_kernel, dim3(1), dim3(64), 0, stream, ws, counts, out);
}

// Round 8
// 653.098 us; speedup vs baseline: 10.3915x; 1.3463x over previous
//
#include <hip/hip_runtime.h>
#include <math.h>

#define NB 64
#define NV 128
#define NEDGE_PER 8128
#define N_EDGE (NB * NEDGE_PER)   // 520192
#define N_EX (NB * NV)            // 8192
#define BID_ROUNDS 64
#define ARR_CAP 128

// workspace layout (doubles):
// ws[0..63]    per-sample SmoothL1 sums
// ws[64]       existence BCE sum
// ws[128..383] edge BCE partials (256 blocks)

typedef unsigned long long u64;
typedef unsigned int uint2v __attribute__((ext_vector_type(2)));

__device__ __forceinline__ float sl1f(float d) {
    d = fabsf(d);
    return d < 1.0f ? 0.5f * d * d : d - 0.5f;
}
__device__ __forceinline__ unsigned umin2(unsigned a, unsigned b) { return a < b ? a : b; }

// ---- cross-lane helpers ---------------------------------------------------

template <int CTRL>
__device__ __forceinline__ int dpp_i(int x) {
    return __builtin_amdgcn_update_dpp(0, x, CTRL, 0xF, 0xF, true);
}

// Monotone u32 key of f32; low 8 bits = column idx (1..128). Exact ties break
// to lowest idx; exact f32 minv is re-read from the winning lane so duals stay
// accurate. Sub-quantum mis-picks only swap near-optimal alternates.
__device__ __forceinline__ unsigned f2key(float x, int idx) {
    unsigned b = __float_as_uint(x);
    unsigned m = (unsigned)(((int)b) >> 31) | 0x80000000u;
    return ((b ^ m) & ~0xFFu) | (unsigned)idx;
}
// ARR key: bit 8 = assigned-flag (prefer unassigned among ties).
__device__ __forceinline__ unsigned f2key_arr(float x, bool assigned, int idx) {
    unsigned b = __float_as_uint(x);
    unsigned m = (unsigned)(((int)b) >> 31) | 0x80000000u;
    return ((b ^ m) & ~0x1FFu) | (assigned ? 0x100u : 0u) | (unsigned)idx;
}
// bid key: monotone map of bid >= 0, low 8 bits = row idx; max-reduce. >0 always.
__device__ __forceinline__ unsigned bidkey(float b, int row) {
    return ((__float_as_uint(b) | 0x80000000u) & ~0xFFu) | (unsigned)row;
}

// 64-lane min over 32-bit packed keys, broadcast to all lanes.
__device__ __forceinline__ unsigned wave_minkey32(unsigned k) {
    { unsigned o = (unsigned)dpp_i<0xB1>((int)k);  k = umin2(k, o); }
    { unsigned o = (unsigned)dpp_i<0x4E>((int)k);  k = umin2(k, o); }
    { unsigned o = (unsigned)dpp_i<0x141>((int)k); k = umin2(k, o); }
    { unsigned o = (unsigned)dpp_i<0x140>((int)k); k = umin2(k, o); }
#if __has_builtin(__builtin_amdgcn_permlane16_swap)
    { uint2v r = __builtin_amdgcn_permlane16_swap(k, k, false, false);
      k = umin2(k, umin2(r.x, r.y)); }
#else
    { k = umin2(k, (unsigned)__shfl_xor((int)k, 16)); }
#endif
#if __has_builtin(__builtin_amdgcn_permlane32_swap)
    { uint2v r = __builtin_amdgcn_permlane32_swap(k, k, false, false);
      k = umin2(k, umin2(r.x, r.y)); }
#else
    { k = umin2(k, (unsigned)__shfl_xor((int)k, 32)); }
#endif
    return k;
}

// two-smallest merge; requires k1<=k2 and o1<=o2 (self-pair merge harmless).
__device__ __forceinline__ void min2m(unsigned& k1, unsigned& k2, unsigned o1, unsigned o2) {
    if (k1 <= o1) {
        k2 = umin2(k2, o1);
    } else {
        k2 = umin2(o2, k1);
        k1 = o1;
    }
}
// 64-lane (min, 2nd-min) over per-lane sorted pairs; broadcast.
__device__ __forceinline__ void wave_min2_32(unsigned& k1, unsigned& k2) {
    { unsigned o1 = (unsigned)dpp_i<0xB1>((int)k1),  o2 = (unsigned)dpp_i<0xB1>((int)k2);  min2m(k1, k2, o1, o2); }
    { unsigned o1 = (unsigned)dpp_i<0x4E>((int)k1),  o2 = (unsigned)dpp_i<0x4E>((int)k2);  min2m(k1, k2, o1, o2); }
    { unsigned o1 = (unsigned)dpp_i<0x141>((int)k1), o2 = (unsigned)dpp_i<0x141>((int)k2); min2m(k1, k2, o1, o2); }
    { unsigned o1 = (unsigned)dpp_i<0x140>((int)k1), o2 = (unsigned)dpp_i<0x140>((int)k2); min2m(k1, k2, o1, o2); }
#if __has_builtin(__builtin_amdgcn_permlane16_swap)
    { uint2v r1 = __builtin_amdgcn_permlane16_swap(k1, k1, false, false);
      uint2v r2 = __builtin_amdgcn_permlane16_swap(k2, k2, false, false);
      min2m(k1, k2, r1.x, r2.x); min2m(k1, k2, r1.y, r2.y); }
#else
    { unsigned o1 = (unsigned)__shfl_xor((int)k1, 16), o2 = (unsigned)__shfl_xor((int)k2, 16); min2m(k1, k2, o1, o2); }
#endif
#if __has_builtin(__builtin_amdgcn_permlane32_swap)
    { uint2v r1 = __builtin_amdgcn_permlane32_swap(k1, k1, false, false);
      uint2v r2 = __builtin_amdgcn_permlane32_swap(k2, k2, false, false);
      min2m(k1, k2, r1.x, r2.x); min2m(k1, k2, r1.y, r2.y); }
#else
    { unsigned o1 = (unsigned)__shfl_xor((int)k1, 32), o2 = (unsigned)__shfl_xor((int)k2, 32); min2m(k1, k2, o1, o2); }
#endif
}

__device__ __forceinline__ int rl_i(int v, int sl) {
    return __builtin_amdgcn_readlane(v, sl);
}
__device__ __forceinline__ float rl_f(float v, int sl) {
    return __int_as_float(__builtin_amdgcn_readlane(__float_as_int(v), sl));
}

// ---- Hungarian: swizzled cost planes + colred + auction + ARR + SAP -------

// cost plane layout: entry (0-based row r, 0-based col-half c0) stored at
// r*64 + (c0 ^ (r&31)) -> 2-way banks for both row-broadcast and row-scan.

__global__ __launch_bounds__(64, 1) void hungarian_kernel(
    const float* __restrict__ pv,     // [B,V,3]
    const float* __restrict__ pe,     // [B,V]
    const float* __restrict__ tv,     // [B,V,3]
    const int*   __restrict__ counts, // [B]
    double* __restrict__ ws_sl1)      // [B]
{
    const int b = blockIdx.x;
    const int lane = threadIdx.x;
    const int c = counts[b];

    __shared__ float  s_costA[NV * 64];  // cols 1..64   (32 KB, swizzled)
    __shared__ float  s_costB[NV * 64];  // cols 65..128 (32 KB, swizzled)
    __shared__ float4 s_row[NV];
    __shared__ float  s_pe[NV];
    __shared__ float  s_v[NV];           // column potentials (LDS master copy)
    __shared__ float  s_u[NV];           // row potentials
    __shared__ int    s_x[NV];           // row -> col (0 = free)
    __shared__ float  s_rm1[NV], s_rm2[NV];
    __shared__ unsigned s_bid[NV];

    const float* pvb = pv + (size_t)b * NV * 3;
    const float* peb = pe + (size_t)b * NV;
    const float* tvb = tv + (size_t)b * NV * 3;

    // lane owns rows/cols (1-based): rA=jA=lane+1, rB=jB=lane+65
    {
        float x0 = pvb[lane * 3 + 0], y0 = pvb[lane * 3 + 1], z0 = pvb[lane * 3 + 2];
        float x1 = pvb[(lane + 64) * 3 + 0], y1 = pvb[(lane + 64) * 3 + 1], z1 = pvb[(lane + 64) * 3 + 2];
        float e0 = peb[lane], e1 = peb[lane + 64];
        s_row[lane]      = make_float4(x0, y0, z0, fabsf(e0 - 1.0f));
        s_row[lane + 64] = make_float4(x1, y1, z1, fabsf(e1 - 1.0f));
        s_pe[lane]       = e0;
        s_pe[lane + 64]  = e1;
    }
    const float tAx = tvb[lane * 3 + 0], tAy = tvb[lane * 3 + 1], tAz = tvb[lane * 3 + 2];
    const float tBx = tvb[(lane + 64) * 3 + 0], tBy = tvb[(lane + 64) * 3 + 1], tBz = tvb[(lane + 64) * 3 + 2];

    const int jA = lane + 1, jB = lane + 65;
    const int rA = lane + 1, rB = lane + 65;
    const bool realA = (jA <= c), realB = (jB <= c);

    __syncthreads();

    // ---- Phase 0: build swizzled cost planes (f32-exact, reference order) --
    #pragma unroll 4
    for (int r = 0; r < NV; ++r) {
        float4 row = s_row[r];
        float per = s_pe[r];
        float cAv = realA ? (((fabsf(row.x - tAx) + fabsf(row.y - tAy)) + fabsf(row.z - tAz)) + row.w) : per;
        float cBv = realB ? (((fabsf(row.x - tBx) + fabsf(row.y - tBy)) + fabsf(row.z - tBz)) + row.w) : per;
        const int a = r * 64 + (lane ^ (r & 31));
        s_costA[a] = cAv;
        s_costB[a] = cBv;
    }
    __syncthreads();

    // ---- Phase A: column reduction (v[j] = min_i C[i][j]) -----------------
    float bestA = 3.4e38f, bestB = 3.4e38f;
    #pragma unroll 4
    for (int r = 0; r < NV; ++r) {
        const int a = r * 64 + (lane ^ (r & 31));
        bestA = fminf(bestA, s_costA[a]);
        bestB = fminf(bestB, s_costB[a]);
    }
    float vA = bestA, vB = bestB;   // this lane's column potentials
    float uA = 0.0f, uB = 0.0f;
    int pA = 0, pB = 0;             // col -> row (0 = free)
    s_v[jA - 1] = vA; s_v[jB - 1] = vB;
    s_x[rA - 1] = 0;  s_x[rB - 1] = 0;
    s_u[rA - 1] = 0.0f; s_u[rB - 1] = 0.0f;

    // ---- Phase B': Jacobi auction rounds (parallel row bids) --------------
    // Exact bids (gamma = m2-m1): v only decreases => u+v <= C stays feasible;
    // winner edges exactly tight. Early exits: converged / stragglers-only /
    // price-war stall (no free-count progress 2 rounds).
    int prevFree = NV + 1, stall = 0;
    for (int round = 0; round < BID_ROUNDS; ++round) {
        const int xAcur = s_x[rA - 1];
        const int xBcur = s_x[rB - 1];
        const u64 fA = __ballot(xAcur == 0);
        const u64 fB = __ballot(xBcur == 0);
        const int nfree = __popcll(fA) + __popcll(fB);
        if (nfree == 0 || nfree <= 8) break;
        if (nfree >= prevFree) { if (++stall >= 2) break; } else stall = 0;
        prevFree = nfree;

        s_bid[jA - 1] = 0u;
        s_bid[jB - 1] = 0u;

        // scan my free rows (exact f32 min/second-min, rotated tie-break)
        #pragma unroll
        for (int half = 0; half < 2; ++half) {
            const int ri = (half == 0) ? rA : rB;            // 1-based row
            const int xcur = (half == 0) ? xAcur : xBcur;
            if (xcur != 0) continue;
            const int r0 = ri - 1;
            const int swz = r0 & 31;
            float m1 = 3.4e38f, m2 = 3.4e38f;
            int j1 = 0, rot1 = 1000;
            #pragma unroll 4
            for (int j0 = 0; j0 < 64; ++j0) {
                const int a = r0 * 64 + (j0 ^ swz);
                float ca = s_costA[a] - s_v[j0];
                float cb = s_costB[a] - s_v[j0 + 64];
                int rotA = (j0 + 1 - ri) & 127;
                int rotB = (j0 + 65 - ri) & 127;
                if (ca < m1 || (ca == m1 && rotA < rot1)) { m2 = m1; m1 = ca; j1 = j0 + 1; rot1 = rotA; }
                else if (ca < m2) m2 = ca;
                if (cb < m1 || (cb == m1 && rotB < rot1)) { m2 = m1; m1 = cb; j1 = j0 + 65; rot1 = rotB; }
                else if (cb < m2) m2 = cb;
            }
            s_rm1[r0] = m1;
            s_rm2[r0] = m2;
            atomicMax(&s_bid[j1 - 1], bidkey(m2 - m1, ri));
        }

        // column accept (this lane's two columns)
        {
            unsigned bk = s_bid[jA - 1];
            if (bk != 0u) {
                const int w = (int)(bk & 0xFFu);
                float m1w = s_rm1[w - 1], m2w = s_rm2[w - 1];
                vA -= (m2w - m1w);
                s_v[jA - 1] = vA;
                int old = pA; pA = w;
                s_x[w - 1] = jA;
                s_u[w - 1] = m2w;
                if (old) s_x[old - 1] = 0;
            }
        }
        {
            unsigned bk = s_bid[jB - 1];
            if (bk != 0u) {
                const int w = (int)(bk & 0xFFu);
                float m1w = s_rm1[w - 1], m2w = s_rm2[w - 1];
                vB -= (m2w - m1w);
                s_v[jB - 1] = vB;
                int old = pB; pB = w;
                s_x[w - 1] = jB;
                s_u[w - 1] = m2w;
                if (old) s_x[old - 1] = 0;
            }
        }
    }

    // load post-round row state into registers
    uA = s_u[rA - 1]; uB = s_u[rB - 1];
    u64 mA = __ballot(s_x[rA - 1] == 0);
    u64 mB = __ballot(s_x[rB - 1] == 0);
    u64 dA = 0ull, dB = 0ull;

    // ---- Phase B: serial ARR for leftovers (tie-skip, clamped duals) ------
    int steps = 0;
    while ((mA | mB) != 0ull && steps < ARR_CAP) {
        ++steps;
        const int i0 = mA ? (__builtin_ctzll(mA) + 1) : (__builtin_ctzll(mB) + 65);
        const bool hi = (i0 > 64);
        const int sl = (i0 - 1) & 63;
        const int ri0 = i0 - 1;
        const int a = ri0 * 64 + (lane ^ (ri0 & 31));

        const float rjA = s_costA[a] - vA;
        const float rjB = s_costB[a] - vB;

        unsigned k1 = f2key_arr(rjA, pA != 0, jA);
        unsigned k2 = f2key_arr(rjB, pB != 0, jB);
        if (k2 < k1) { unsigned t = k1; k1 = k2; k2 = t; }
        wave_min2_32(k1, k2);

        const int j1 = (int)(__builtin_amdgcn_readfirstlane(k1) & 0xFFu);
        const int j2 = (int)(__builtin_amdgcn_readfirstlane(k2) & 0xFFu);
        const bool h1 = (j1 > 64); const int s1 = (j1 - 1) & 63;
        const bool h2 = (j2 > 64); const int s2 = (j2 - 1) & 63;
        const float m1 = rl_f(h1 ? rjB : rjA, s1);
        const float m2 = rl_f(h2 ? rjB : rjA, s2);
        const int kdisp = rl_i(h1 ? pB : pA, s1);

        if (hi) mB &= ~(1ull << sl); else mA &= ~(1ull << sl);

        if (kdisp != 0 && !(m2 > m1)) {
            if (hi) dB |= (1ull << sl); else dA |= (1ull << sl);
            continue;
        }
        const float dlt = fmaxf(m2 - m1, 0.0f);
        if (jA == j1) { vA -= dlt; pA = i0; }
        if (jB == j1) { vB -= dlt; pB = i0; }
        if (rA == i0) { uA = m2; }
        if (rB == i0) { uB = m2; }
        if (kdisp != 0) {
            if (kdisp > 64) mB |= (1ull << (kdisp - 65)); else mA |= (1ull << (kdisp - 1));
        }
    }
    mA |= dA;
    mB |= dB;

    // ---- Phase C: shortest augmenting paths, shift-trick ------------------
    const float INF = 3.4e38f;
    while ((mA | mB) != 0ull) {
        const int f = mA ? (__builtin_ctzll(mA) + 1) : (__builtin_ctzll(mB) + 65);
        if (f <= 64) mA &= ~(1ull << (f - 1)); else mB &= ~(1ull << (f - 65));

        float minvA = INF, minvB = INF;
        int wayA = 0, wayB = 0;
        bool cuA = false, cuB = false;
        float SuseA = 0.0f, SuseB = 0.0f;
        bool rsA = (rA == f), rsB = (rB == f);
        float SsetA = 0.0f, SsetB = 0.0f;
        int j0 = 0;
        int i0 = f;
        float S = 0.0f;

        float u0 = rl_f((f > 64) ? uB : uA, (f - 1) & 63);
        float pre = u0;
        int ri0 = f - 1;
        int a = ri0 * 64 + (lane ^ (ri0 & 31));
        float cA = s_costA[a];
        float cB = s_costB[a];

        for (;;) {
            if (!cuA) { float cur = (cA - pre) - vA; if (cur < minvA) { minvA = cur; wayA = j0; } }
            if (!cuB) { float cur = (cB - pre) - vB; if (cur < minvB) { minvB = cur; wayB = j0; } }

            unsigned k = umin2(f2key(minvA, jA), f2key(minvB, jB));
            k = wave_minkey32(k);

            const int idx = (int)(__builtin_amdgcn_readfirstlane(k) & 0xFFu);
            const bool hij = (idx > 64);
            const int slj = (idx - 1) & 63;
            // cndmask-then-readlane: 2 readlanes on the chain, not 4
            const float Snew = rl_f(hij ? minvB : minvA, slj);
            i0 = rl_i(hij ? pB : pA, slj);
            j0 = idx;

            if (jA == j0) { cuA = true; SuseA = Snew; minvA = INF; }
            if (jB == j0) { cuB = true; SuseB = Snew; minvB = INF; }
            S = Snew;
            if (i0 == 0) break;

            if (rA == i0) { rsA = true; SsetA = Snew; }
            if (rB == i0) { rsB = true; SsetB = Snew; }
            u0 = rl_f((i0 > 64) ? uB : uA, (i0 - 1) & 63);
            pre = u0 - S;
            ri0 = i0 - 1;
            a = ri0 * 64 + (lane ^ (ri0 & 31));
            cA = s_costA[a];
            cB = s_costB[a];
        }

        if (cuA) vA -= (S - SuseA);
        if (cuB) vB -= (S - SuseB);
        if (rsA) uA += (S - SsetA);
        if (rsB) uB += (S - SsetB);

        // augment along way[] chain
        int j = j0;
        while (j != 0) {
            int j1 = rl_i((j <= 64) ? wayA : wayB, (j - 1) & 63);
            int pnew = (j1 == 0) ? f : rl_i((j1 <= 64) ? pA : pB, (j1 - 1) & 63);
            if (jA == j) pA = pnew;
            if (jB == j) pB = pnew;
            j = j1;
        }
    }

    // ---- SmoothL1 over matched pairs (cols < c) ---------------------------
    double acc = 0.0;
    if (lane < c) {
        float4 prow = s_row[pA - 1];
        acc += (double)(sl1f(prow.x - tAx) + sl1f(prow.y - tAy) + sl1f(prow.z - tAz));
    }
    if (lane + 64 < c) {
        float4 prow = s_row[pB - 1];
        acc += (double)(sl1f(prow.x - tBx) + sl1f(prow.y - tBy) + sl1f(prow.z - tBz));
    }
    for (int off = 1; off < 64; off <<= 1) acc += __shfl_xor(acc, off);
    if (lane == 0) ws_sl1[b] = acc;
}

// ---- BCE / finalize -------------------------------------------------------

__device__ __forceinline__ double bce_term(float p, float t) {
    float logp = fmaxf(logf(p), -100.0f);
    float logq = fmaxf(logf(1.0f - p), -100.0f);
    return (double)(-(t * logp + (1.0f - t) * logq));
}

__global__ __launch_bounds__(256) void bce_exist_kernel(
    const float* __restrict__ pe, const int* __restrict__ te, double* __restrict__ out)
{
    const int tid = threadIdx.x;
    double acc = 0.0;
    for (int i = tid; i < N_EX; i += 256)
        acc += bce_term(pe[i], (float)te[i]);
    for (int off = 1; off < 64; off <<= 1) acc += __shfl_xor(acc, off);
    __shared__ double s[4];
    if ((tid & 63) == 0) s[tid >> 6] = acc;
    __syncthreads();
    if (tid == 0) out[0] = s[0] + s[1] + s[2] + s[3];
}

__global__ __launch_bounds__(256) void bce_edge_kernel(
    const float* __restrict__ p, const float* __restrict__ t, double* __restrict__ out)
{
    const int tid = threadIdx.x;
    double acc = 0.0;
    for (int i = blockIdx.x * 256 + tid; i < N_EDGE; i += 256 * 256)
        acc += bce_term(p[i], t[i]);
    for (int off = 1; off < 64; off <<= 1) acc += __shfl_xor(acc, off);
    __shared__ double s[4];
    if ((tid & 63) == 0) s[tid >> 6] = acc;
    __syncthreads();
    if (tid == 0) out[blockIdx.x] = s[0] + s[1] + s[2] + s[3];
}

__global__ __launch_bounds__(64) void finalize_kernel(
    const double* __restrict__ ws, const int* __restrict__ counts, float* __restrict__ out)
{
    const int lane = threadIdx.x;
    double vsum = ws[lane];
    double csum = (double)counts[lane];
    double edsum = 0.0;
    for (int k = lane; k < 256; k += 64) edsum += ws[128 + k];
    for (int off = 1; off < 64; off <<= 1) {
        vsum  += __shfl_xor(vsum, off);
        csum  += __shfl_xor(csum, off);
        edsum += __shfl_xor(edsum, off);
    }
    if (lane == 0) {
        double vloss  = vsum / (3.0 * csum);
        double eloss  = ws[64] / (double)N_EX;
        double edloss = edsum / (double)N_EDGE;
        double total  = vloss + eloss + edloss;
        out[0] = (float)total;
        out[1] = (float)vloss;
        out[2] = (float)eloss;
        out[3] = (float)edloss;
    }
}

extern "C" void kernel_launch(void* const* d_in, const int* in_sizes, int n_in,
                              void* d_out, int out_size, void* d_ws, size_t ws_size,
                              hipStream_t stream) {
    const float* pv     = (const float*)d_in[0];
    const float* pe     = (const float*)d_in[1];
    const float* pedge  = (const float*)d_in[2];
    const float* tv     = (const float*)d_in[3];
    const int*   te     = (const int*)d_in[4];
    const float* elab   = (const float*)d_in[5];
    const int*   counts = (const int*)d_in[6];
    double* ws = (double*)d_ws;
    float* out = (float*)d_out;

    hipLaunchKernelGGL(hungarian_kernel, dim3(NB), dim3(64), 0, stream, pv, pe, tv, counts, ws);
    hipLaunchKernelGGL(bce_exist_kernel, dim3(1), dim3(256), 0, stream, pe, te, ws + 64);
    hipLaunchKernelGGL(bce_edge_kernel, dim3(256), dim3(256), 0, stream, pedge, elab, ws + 128);
    hipLaunchKernelGGL(finalize_kernel, dim3(1), dim3(64), 0, stream, ws, counts, out);
}